// Round 12
// baseline (456.055 us; speedup 1.0000x reference)
//
#include <hip/hip_runtime.h>
#include <hip/hip_fp16.h>

constexpr int NN = 50000;   // nodes
constexpr int NE = 800000;  // edges
constexpr int NG = 64;      // graphs
constexpr int DI = 64;      // in dim
constexpr int DH = 128;     // hidden dim
constexpr int DO = 3;       // out dim

constexpr int SCAN_B = 256;
constexpr int NB_SCAN = (NN + SCAN_B - 1) / SCAN_B;  // 196
constexpr int NBK = 196;          // buckets of 256 nodes (dst >> 8)
constexpr int SS = NBK * 8;       // sub-streams (bucket x blockIdx&7) = 1568

typedef unsigned int u32;

// ---------------- bf16 / fp16 helpers ----------------
__device__ inline float blo(u32 u) { return __uint_as_float(u << 16); }
__device__ inline float bhi(u32 u) { return __uint_as_float(u & 0xffff0000u); }
__device__ inline u32 f2b(float f) {  // RNE round to bf16 (16-bit pattern)
    u32 u = __float_as_uint(f);
    return (u + 0x7fffu + ((u >> 16) & 1u)) >> 16;
}
__device__ inline float wof(u32 e) {  // fp16 weight from high 16 bits
    __half h;
    reinterpret_cast<ushort&>(h) = (ushort)(e >> 16);
    return __half2float(h);
}
__device__ inline void fma8(float w, uint4 v, float acc[8]) {
    acc[0] = fmaf(w, blo(v.x), acc[0]); acc[1] = fmaf(w, bhi(v.x), acc[1]);
    acc[2] = fmaf(w, blo(v.y), acc[2]); acc[3] = fmaf(w, bhi(v.y), acc[3]);
    acc[4] = fmaf(w, blo(v.z), acc[4]); acc[5] = fmaf(w, bhi(v.z), acc[5]);
    acc[6] = fmaf(w, blo(v.w), acc[6]); acc[7] = fmaf(w, bhi(v.w), acc[7]);
}

// ---------------- fused: x -> bf16 AND zero cntN/cntS ----------------
__global__ void k_init(const float* __restrict__ x, uint4* __restrict__ xb,
                       int* __restrict__ cntN, int* __restrict__ cntS) {
    int i = blockIdx.x * blockDim.x + threadIdx.x;
    if (i < NN * DI / 8) {
        float4 a = reinterpret_cast<const float4*>(x)[i * 2];
        float4 b = reinterpret_cast<const float4*>(x)[i * 2 + 1];
        uint4 o;
        o.x = f2b(a.x) | (f2b(a.y) << 16);
        o.y = f2b(a.z) | (f2b(a.w) << 16);
        o.z = f2b(b.x) | (f2b(b.y) << 16);
        o.w = f2b(b.z) | (f2b(b.w) << 16);
        xb[i] = o;
    }
    if (i < NN) cntN[i] = 0;
    if (i < SS) cntS[i] = 0;
}

// ---------------- histograms: per-node in-degree + per-(bucket,xcd) counts ----------------
__global__ void k_hist(const int* __restrict__ dst, int* __restrict__ cntN,
                       int* __restrict__ cntS) {
    int e = blockIdx.x * blockDim.x + threadIdx.x;
    if (e < NE) {
        int d = dst[e];
        atomicAdd(&cntN[d], 1);
        atomicAdd(&cntS[(d >> 8) * 8 + (blockIdx.x & 7)], 1);
    }
}

__global__ void k_scan1(const int* __restrict__ cnt, int* __restrict__ rowptr,
                        int* __restrict__ partial) {
    __shared__ int sm[SCAN_B];
    int i = blockIdx.x * SCAN_B + threadIdx.x;
    int v = (i < NN) ? cnt[i] : 0;
    sm[threadIdx.x] = v;
    __syncthreads();
    for (int off = 1; off < SCAN_B; off <<= 1) {
        int add = (threadIdx.x >= off) ? sm[threadIdx.x - off] : 0;
        __syncthreads();
        sm[threadIdx.x] += add;
        __syncthreads();
    }
    if (i < NN) rowptr[i] = sm[threadIdx.x] - v;  // block-local exclusive
    if (threadIdx.x == SCAN_B - 1) partial[blockIdx.x] = sm[SCAN_B - 1];
}

__global__ void k_scan2(int* partial) {  // single block, NB_SCAN <= 256
    __shared__ int sm[SCAN_B];
    int v = (threadIdx.x < NB_SCAN) ? partial[threadIdx.x] : 0;
    sm[threadIdx.x] = v;
    __syncthreads();
    for (int off = 1; off < SCAN_B; off <<= 1) {
        int add = (threadIdx.x >= off) ? sm[threadIdx.x - off] : 0;
        __syncthreads();
        sm[threadIdx.x] += add;
        __syncthreads();
    }
    if (threadIdx.x < NB_SCAN) partial[threadIdx.x] = sm[threadIdx.x] - v;  // exclusive
}

// finalizes rowptr and computes dinv from cntN
__global__ void k_scan3(int* __restrict__ rowptr, const int* __restrict__ partial,
                        const int* __restrict__ cntN, float* __restrict__ dinv) {
    int i = blockIdx.x * blockDim.x + threadIdx.x;
    if (i < NN) {
        rowptr[i] += partial[i >> 8];
        dinv[i] = rsqrtf((float)(cntN[i] + 1));  // +1 self-loop
    }
    if (i == NN) rowptr[NN] = NE;
}

// scan over SS sub-stream counts (single block, 7 values per thread)
__global__ __launch_bounds__(256) void k_scanS(const int* __restrict__ cntS,
                                               int* __restrict__ ssOff,
                                               int* __restrict__ ssCur) {
    __shared__ int sm[256];
    const int t = threadIdx.x;
    const int base = t * 7;
    int v[7];
    int s = 0;
#pragma unroll
    for (int i = 0; i < 7; ++i) {
        int idx = base + i;
        v[i] = (idx < SS) ? cntS[idx] : 0;
        s += v[i];
    }
    sm[t] = s;
    __syncthreads();
    for (int off = 1; off < 256; off <<= 1) {
        int add = (t >= off) ? sm[t - off] : 0;
        __syncthreads();
        sm[t] += add;
        __syncthreads();
    }
    int run = t ? sm[t - 1] : 0;
#pragma unroll
    for (int i = 0; i < 7; ++i) {
        int idx = base + i;
        if (idx < SS) { ssOff[idx] = run; ssCur[idx] = run; }
        run += v[i];
    }
    if (t == 255) ssOff[SS] = NE;
}

// pass A: bin edges into (bucket, blockIdx&7) staging sub-streams (XCD-local appends)
__global__ void k_fillA(const int* __restrict__ src, const int* __restrict__ dst,
                        const float* __restrict__ dinv, int* __restrict__ ssCur,
                        uint2* __restrict__ stage) {
    int e = blockIdx.x * blockDim.x + threadIdx.x;
    if (e >= NE) return;
    int s = src[e], d = dst[e];
    float w = dinv[s] * dinv[d];
    __half hw = __float2half(w);
    u32 packed = ((u32)reinterpret_cast<ushort&>(hw) << 16) | (u32)s;
    int slot = atomicAdd(&ssCur[(d >> 8) * 8 + (blockIdx.x & 7)], 1);
    stage[slot] = make_uint2(packed, (u32)d);
}

// pass B: one block per bucket; LDS cursors; writes confined to the bucket's csr window
__global__ __launch_bounds__(256) void k_fillB(const uint2* __restrict__ stage,
                                               const int* __restrict__ ssOff,
                                               const int* __restrict__ rowptr,
                                               u32* __restrict__ csr) {
    __shared__ int cur[256];
    const int b = blockIdx.x;
    const int t = threadIdx.x;
    const int n = b * 256 + t;
    cur[t] = (n < NN) ? rowptr[n] : 0;
    __syncthreads();
    const int beg = ssOff[b * 8];
    const int end = ssOff[b * 8 + 8];
    for (int i = beg + t; i < end; i += 256) {
        uint2 en = stage[i];
        int slot = atomicAdd(&cur[en.y & 255u], 1);
        csr[slot] = en.x;
    }
}

// ---------------- gather aggregation over a bf16 table, packed 4B edges ----------------
// out[n] = dinv[n]^2*hb[n] + sum_in w_e * hb[src_e]   (+bias, relu)
template <int D, bool BIAS_RELU, bool BF16OUT>
__global__ __launch_bounds__(256) void k_aggc(const ushort* __restrict__ hb,
                                              const u32* __restrict__ csr,
                                              const int* __restrict__ rowptr,
                                              const float* __restrict__ dinv,
                                              const float* __restrict__ bias,
                                              void* __restrict__ out) {
    constexpr int SUB = D / 8;        // lanes per node (8 for D=64, 16 for D=128)
    constexpr int NPB = 256 / SUB;    // nodes per block
    const int sub = threadIdx.x / SUB;
    const int sl = threadIdx.x % SUB;
    const int node = blockIdx.x * NPB + sub;
    if (node >= NN) return;

    const float dn = dinv[node];
    float acc[8];
    {
        uint4 v = *reinterpret_cast<const uint4*>(hb + (size_t)node * D + sl * 8);
        float w = dn * dn;
        acc[0] = w * blo(v.x); acc[1] = w * bhi(v.x);
        acc[2] = w * blo(v.y); acc[3] = w * bhi(v.y);
        acc[4] = w * blo(v.z); acc[5] = w * bhi(v.z);
        acc[6] = w * blo(v.w); acc[7] = w * bhi(v.w);
    }
    int j = rowptr[node];
    const int end = rowptr[node + 1];
    // peel to 16B boundary for uint4 edge loads
    while ((j & 3) && j < end) {
        u32 e = csr[j];
        uint4 g = *reinterpret_cast<const uint4*>(hb + (size_t)(e & 0xffffu) * D + sl * 8);
        fma8(wof(e), g, acc);
        ++j;
    }
    // main: 4 edges per iteration (one uint4 index load, 4 independent gathers)
    for (; j + 4 <= end; j += 4) {
        uint4 p = *reinterpret_cast<const uint4*>(&csr[j]);
        uint4 g0 = *reinterpret_cast<const uint4*>(hb + (size_t)(p.x & 0xffffu) * D + sl * 8);
        uint4 g1 = *reinterpret_cast<const uint4*>(hb + (size_t)(p.y & 0xffffu) * D + sl * 8);
        uint4 g2 = *reinterpret_cast<const uint4*>(hb + (size_t)(p.z & 0xffffu) * D + sl * 8);
        uint4 g3 = *reinterpret_cast<const uint4*>(hb + (size_t)(p.w & 0xffffu) * D + sl * 8);
        fma8(wof(p.x), g0, acc);
        fma8(wof(p.y), g1, acc);
        fma8(wof(p.z), g2, acc);
        fma8(wof(p.w), g3, acc);
    }
    while (j < end) {
        u32 e = csr[j];
        uint4 g = *reinterpret_cast<const uint4*>(hb + (size_t)(e & 0xffffu) * D + sl * 8);
        fma8(wof(e), g, acc);
        ++j;
    }
    if (BIAS_RELU) {
        float4 b0 = *reinterpret_cast<const float4*>(bias + sl * 8);
        float4 b1 = *reinterpret_cast<const float4*>(bias + sl * 8 + 4);
        acc[0] = fmaxf(acc[0] + b0.x, 0.f); acc[1] = fmaxf(acc[1] + b0.y, 0.f);
        acc[2] = fmaxf(acc[2] + b0.z, 0.f); acc[3] = fmaxf(acc[3] + b0.w, 0.f);
        acc[4] = fmaxf(acc[4] + b1.x, 0.f); acc[5] = fmaxf(acc[5] + b1.y, 0.f);
        acc[6] = fmaxf(acc[6] + b1.z, 0.f); acc[7] = fmaxf(acc[7] + b1.w, 0.f);
    }
    if (BF16OUT) {
        uint4 o;
        o.x = f2b(acc[0]) | (f2b(acc[1]) << 16);
        o.y = f2b(acc[2]) | (f2b(acc[3]) << 16);
        o.z = f2b(acc[4]) | (f2b(acc[5]) << 16);
        o.w = f2b(acc[6]) | (f2b(acc[7]) << 16);
        *reinterpret_cast<uint4*>(reinterpret_cast<ushort*>(out) + (size_t)node * D + sl * 8) = o;
    } else {
        float* op = reinterpret_cast<float*>(out) + (size_t)node * D + sl * 8;
        *reinterpret_cast<float4*>(op) = make_float4(acc[0], acc[1], acc[2], acc[3]);
        *reinterpret_cast<float4*>(op + 4) = make_float4(acc[4], acc[5], acc[6], acc[7]);
    }
}

// ---------------- GEMM: C_bf16[NN,DH] = A_bf16[NN,DIN] @ W_f32[DIN,DH] (+bias, relu) ----------------
__device__ inline float4 fmaf4(float s, float4 w, float4 a) {
    a.x = fmaf(s, w.x, a.x); a.y = fmaf(s, w.y, a.y);
    a.z = fmaf(s, w.z, a.z); a.w = fmaf(s, w.w, a.w);
    return a;
}

template <int DIN, bool BIAS_RELU>
__global__ __launch_bounds__(256) void k_gemm3b(const ushort* __restrict__ A,
                                                const float* __restrict__ W,
                                                const float* __restrict__ bias,
                                                u32* __restrict__ C) {
    constexpr int KT = 32;
    constexpr int NT = DIN / KT;
    constexpr int AP = KT + 4;
    __shared__ float sW[KT * DH];   // [k][c] row-major, 16 KB
    __shared__ float sA[64 * AP];   // [r][k] padded
    const int t = threadIdx.x;
    const int cg = t & 31;
    const int rg = t >> 5;
    const int row0 = blockIdx.x * 64;
    const int sr = t >> 2;
    const int kq = t & 3;

    float4 acc[8];
#pragma unroll
    for (int j = 0; j < 8; ++j) acc[j] = make_float4(0.f, 0.f, 0.f, 0.f);

    for (int tile = 0; tile < NT; ++tile) {
        if (tile) __syncthreads();
        {
            const float4* Wg = reinterpret_cast<const float4*>(W + tile * KT * DH);
            float4* sW4 = reinterpret_cast<float4*>(sW);
#pragma unroll
            for (int i = 0; i < (KT * DH / 4) / 256; ++i)
                sW4[t + 256 * i] = Wg[t + 256 * i];
        }
        {
            int gr = row0 + sr;
            uint4 v = make_uint4(0u, 0u, 0u, 0u);
            if (gr < NN)
                v = *reinterpret_cast<const uint4*>(A + (size_t)gr * DIN + tile * KT + kq * 8);
            *reinterpret_cast<float4*>(&sA[sr * AP + kq * 8]) =
                make_float4(blo(v.x), bhi(v.x), blo(v.y), bhi(v.y));
            *reinterpret_cast<float4*>(&sA[sr * AP + kq * 8 + 4]) =
                make_float4(blo(v.z), bhi(v.z), blo(v.w), bhi(v.w));
        }
        __syncthreads();
#pragma unroll 2
        for (int kk = 0; kk < KT; kk += 4) {
            float4 w0 = *reinterpret_cast<const float4*>(&sW[(kk + 0) * DH + cg * 4]);
            float4 w1 = *reinterpret_cast<const float4*>(&sW[(kk + 1) * DH + cg * 4]);
            float4 w2 = *reinterpret_cast<const float4*>(&sW[(kk + 2) * DH + cg * 4]);
            float4 w3 = *reinterpret_cast<const float4*>(&sW[(kk + 3) * DH + cg * 4]);
#pragma unroll
            for (int j = 0; j < 8; ++j) {
                float4 a = *reinterpret_cast<const float4*>(&sA[(rg * 8 + j) * AP + kk]);
                acc[j] = fmaf4(a.x, w0, acc[j]);
                acc[j] = fmaf4(a.y, w1, acc[j]);
                acc[j] = fmaf4(a.z, w2, acc[j]);
                acc[j] = fmaf4(a.w, w3, acc[j]);
            }
        }
    }
    float4 bb = make_float4(0.f, 0.f, 0.f, 0.f);
    if (BIAS_RELU) bb = *reinterpret_cast<const float4*>(bias + cg * 4);
#pragma unroll
    for (int j = 0; j < 8; ++j) {
        int gr = row0 + rg * 8 + j;
        if (gr < NN) {
            float4 r = acc[j];
            if (BIAS_RELU) {
                r.x = fmaxf(r.x + bb.x, 0.f); r.y = fmaxf(r.y + bb.y, 0.f);
                r.z = fmaxf(r.z + bb.z, 0.f); r.w = fmaxf(r.w + bb.w, 0.f);
            }
            uint2 o = make_uint2(f2b(r.x) | (f2b(r.y) << 16),
                                 f2b(r.z) | (f2b(r.w) << 16));
            *reinterpret_cast<uint2*>(&C[(size_t)gr * (DH / 2) + cg * 2]) = o;
        }
    }
}

// ---------------- pooling (bf16 input, coalesced u32 reads) ----------------
__global__ void k_gstart_zero(const int* __restrict__ batch, int* __restrict__ gstart,
                              float* __restrict__ pooled) {
    int i = blockIdx.x * blockDim.x + threadIdx.x;
    if (i < NG * DH) pooled[i] = 0.0f;
    if (blockIdx.x == 0 && threadIdx.x <= NG) {
        int g = threadIdx.x;
        int lo = 0, hi = NN;
        while (lo < hi) {
            int mid = (lo + hi) >> 1;
            if (batch[mid] < g) lo = mid + 1; else hi = mid;
        }
        gstart[g] = lo;
    }
}

constexpr int POOL_CHUNK = 64;
__global__ __launch_bounds__(256) void k_pool3(const u32* __restrict__ h2b,
                                               const int* __restrict__ batch,
                                               float* __restrict__ pooled) {
    const int c2 = threadIdx.x & 63;   // channel pair (2 bf16 per u32)
    const int q = threadIdx.x >> 6;    // 0..3: 4-way node interleave
    const int n0 = blockIdx.x * POOL_CHUNK;
    const int nEnd = min(n0 + POOL_CHUNK, NN);
    float a0 = 0.f, a1 = 0.f;
    int gcur = -1;
    for (int n = n0 + q; n < nEnd; n += 4) {
        int g = batch[n];
        if (g != gcur) {
            if (gcur >= 0) {
                atomicAdd(&pooled[gcur * DH + c2 * 2], a0);
                atomicAdd(&pooled[gcur * DH + c2 * 2 + 1], a1);
            }
            a0 = a1 = 0.f;
            gcur = g;
        }
        u32 v = h2b[(size_t)n * (DH / 2) + c2];
        a0 += blo(v);
        a1 += bhi(v);
    }
    if (gcur >= 0) {
        atomicAdd(&pooled[gcur * DH + c2 * 2], a0);
        atomicAdd(&pooled[gcur * DH + c2 * 2 + 1], a1);
    }
}

__global__ void k_head(const float* __restrict__ pooled, const int* __restrict__ gstart,
                       const float* __restrict__ Wf, const float* __restrict__ bf,
                       float* __restrict__ out) {
    int t = threadIdx.x;
    if (t >= NG * DO) return;
    int g = t / DO, o = t - g * DO;
    float acc = 0.0f;
    for (int k = 0; k < DH; ++k) acc += pooled[g * DH + k] * Wf[k * DO + o];
    float cnt = fmaxf((float)(gstart[g + 1] - gstart[g]), 1.0f);
    out[t] = acc / cnt + bf[o];
}

extern "C" void kernel_launch(void* const* d_in, const int* in_sizes, int n_in,
                              void* d_out, int out_size, void* d_ws, size_t ws_size,
                              hipStream_t stream) {
    const float* x   = (const float*)d_in[0];
    const int* ei    = (const int*)d_in[1];  // [2, NE] row-major
    const int* batch = (const int*)d_in[2];
    const float* W1  = (const float*)d_in[3];
    const float* b1  = (const float*)d_in[4];
    const float* W2  = (const float*)d_in[5];
    const float* b2  = (const float*)d_in[6];
    const float* Wf  = (const float*)d_in[7];
    const float* bf  = (const float*)d_in[8];
    float* out = (float*)d_out;

    const int* src = ei;
    const int* dst = ei + NE;

    // workspace (4B units; ~42.3 MB total)
    int* cntN     = (int*)d_ws;              // 50048
    int* rowptr   = cntN + 50048;            // 50056 (NN+1 used)
    int* partial  = rowptr + 50056;          // 256
    int* gstart   = partial + 256;           // 80
    int* cntS     = gstart + 80;             // 1600 (SS=1568)
    int* ssOff    = cntS + 1600;             // 1608 (SS+1)
    int* ssCur    = ssOff + 1608;            // 1600
    u32* csr      = (u32*)(ssCur + 1600);    // NE u32 (byte off 420992, 16B-aligned)
    float* dinv   = (float*)(csr + NE);      // 50048
    u32* R1       = (u32*)(dinv + 50048);    // 3.2M units: xb (first 1.6M) then h1b
    u32* R2       = R1 + 3200000;            // 3.2M units: stage/agg1b then tb
    u32* h2b      = R2 + 3200000;            // 3.2M units (NN x 128 bf16)
    float* pooled = (float*)(h2b + 3200000); // 8192

    ushort* xb    = (ushort*)R1;   // NN x 64 bf16 (dead after agg1)
    ushort* h1b   = (ushort*)R1;   // NN x 128 bf16 (written by gemm1, after agg1)
    uint2* stage  = (uint2*)R2;    // NE uint2 = 1.6M u32 (dead after fillB, < agg1 write)
    ushort* agg1b = (ushort*)R2;   // NN x 64 bf16 (dead after gemm1)
    ushort* tb    = (ushort*)R2;   // NN x 128 bf16 (written by gemm2)

    const int B = 256;
    k_init<<<(NN * DI / 8 + B - 1) / B, B, 0, stream>>>(x, (uint4*)xb, cntN, cntS);
    k_hist<<<(NE + B - 1) / B, B, 0, stream>>>(dst, cntN, cntS);
    k_scan1<<<NB_SCAN, SCAN_B, 0, stream>>>(cntN, rowptr, partial);
    k_scan2<<<1, SCAN_B, 0, stream>>>(partial);
    k_scan3<<<(NN + B) / B, B, 0, stream>>>(rowptr, partial, cntN, dinv);
    k_scanS<<<1, 256, 0, stream>>>(cntS, ssOff, ssCur);
    k_fillA<<<(NE + B - 1) / B, B, 0, stream>>>(src, dst, dinv, ssCur, stage);
    k_fillB<<<NBK, 256, 0, stream>>>(stage, ssOff, rowptr, csr);

    const int gemmGrid = (NN + 63) / 64;  // 782

    // layer 1: agg in 64-d (bf16 table), then GEMM (+bias+relu) -> h1 bf16
    k_aggc<DI, false, true><<<(NN + 31) / 32, 256, 0, stream>>>(xb, csr, rowptr, dinv,
                                                                nullptr, agg1b);
    k_gemm3b<DI, true><<<gemmGrid, 256, 0, stream>>>(agg1b, W1, b1, (u32*)h1b);

    // layer 2: GEMM -> t bf16, then agg (+bias+relu) -> h2 bf16
    k_gemm3b<DH, false><<<gemmGrid, 256, 0, stream>>>(h1b, W2, nullptr, (u32*)tb);
    k_aggc<DH, true, true><<<(NN + 15) / 16, 256, 0, stream>>>(tb, csr, rowptr, dinv,
                                                               b2, (void*)h2b);

    // pool + head
    k_gstart_zero<<<32, 256, 0, stream>>>(batch, gstart, pooled);
    k_pool3<<<(NN + POOL_CHUNK - 1) / POOL_CHUNK, 256, 0, stream>>>(h2b, batch, pooled);
    k_head<<<1, 256, 0, stream>>>(pooled, gstart, Wf, bf, out);
}

// Round 13
// 270.055 us; speedup vs baseline: 1.6887x; 1.6887x over previous
//
#include <hip/hip_runtime.h>
#include <hip/hip_fp16.h>

constexpr int NN = 50000;   // nodes
constexpr int NE = 800000;  // edges
constexpr int NG = 64;      // graphs
constexpr int DI = 64;      // in dim
constexpr int DH = 128;     // hidden dim
constexpr int DO = 3;       // out dim

constexpr int SCAN_B = 256;
constexpr int NB_SCAN = (NN + SCAN_B - 1) / SCAN_B;  // 196
constexpr int NBK = 196;                  // dst buckets of 256 nodes (dst >> 8)
constexpr int CHUNK = 4096;               // edges per partition block
constexpr int NCH = (NE + CHUNK - 1) / CHUNK;  // 196 chunks
constexpr int BBTOT = NBK * NCH;          // 38416 (bucket-major [b][c])

typedef unsigned int u32;

// ---------------- bf16 / fp16 helpers ----------------
__device__ inline float blo(u32 u) { return __uint_as_float(u << 16); }
__device__ inline float bhi(u32 u) { return __uint_as_float(u & 0xffff0000u); }
__device__ inline u32 f2b(float f) {  // RNE round to bf16 (16-bit pattern)
    u32 u = __float_as_uint(f);
    return (u + 0x7fffu + ((u >> 16) & 1u)) >> 16;
}
__device__ inline float wof(u32 e) {  // fp16 weight from high 16 bits
    __half h;
    reinterpret_cast<ushort&>(h) = (ushort)(e >> 16);
    return __half2float(h);
}
__device__ inline void fma8(float w, uint4 v, float acc[8]) {
    acc[0] = fmaf(w, blo(v.x), acc[0]); acc[1] = fmaf(w, bhi(v.x), acc[1]);
    acc[2] = fmaf(w, blo(v.y), acc[2]); acc[3] = fmaf(w, bhi(v.y), acc[3]);
    acc[4] = fmaf(w, blo(v.z), acc[4]); acc[5] = fmaf(w, bhi(v.z), acc[5]);
    acc[6] = fmaf(w, blo(v.w), acc[6]); acc[7] = fmaf(w, bhi(v.w), acc[7]);
}

// ---------------- fused: x -> bf16 AND zero cntN ----------------
__global__ void k_init(const float* __restrict__ x, uint4* __restrict__ xb,
                       int* __restrict__ cntN) {
    int i = blockIdx.x * blockDim.x + threadIdx.x;
    if (i < NN * DI / 8) {
        float4 a = reinterpret_cast<const float4*>(x)[i * 2];
        float4 b = reinterpret_cast<const float4*>(x)[i * 2 + 1];
        uint4 o;
        o.x = f2b(a.x) | (f2b(a.y) << 16);
        o.y = f2b(a.z) | (f2b(a.w) << 16);
        o.z = f2b(b.x) | (f2b(b.y) << 16);
        o.w = f2b(b.z) | (f2b(b.w) << 16);
        xb[i] = o;
    }
    if (i < NN) cntN[i] = 0;
}

// ---------------- hist: per-node in-degree atomics + per-(bucket,chunk) LDS counts ----------------
__global__ __launch_bounds__(256) void k_histc(const int* __restrict__ dst,
                                               int* __restrict__ cntN,
                                               int* __restrict__ cntBB) {
    __shared__ int lcnt[NBK];
    const int t = threadIdx.x, c = blockIdx.x;
    for (int b = t; b < NBK; b += 256) lcnt[b] = 0;
    __syncthreads();
    const int base = c * CHUNK;
    const int endE = min(base + CHUNK, NE);
    for (int e = base + t; e < endE; e += 256) {
        int d = dst[e];
        atomicAdd(&cntN[d], 1);
        atomicAdd(&lcnt[d >> 8], 1);
    }
    __syncthreads();
    for (int b = t; b < NBK; b += 256) cntBB[b * NCH + c] = lcnt[b];
}

// ---------------- rowptr scan (over cntN) ----------------
__global__ void k_scan1(const int* __restrict__ cnt, int* __restrict__ rowptr,
                        int* __restrict__ partial) {
    __shared__ int sm[SCAN_B];
    int i = blockIdx.x * SCAN_B + threadIdx.x;
    int v = (i < NN) ? cnt[i] : 0;
    sm[threadIdx.x] = v;
    __syncthreads();
    for (int off = 1; off < SCAN_B; off <<= 1) {
        int add = (threadIdx.x >= off) ? sm[threadIdx.x - off] : 0;
        __syncthreads();
        sm[threadIdx.x] += add;
        __syncthreads();
    }
    if (i < NN) rowptr[i] = sm[threadIdx.x] - v;  // block-local exclusive
    if (threadIdx.x == SCAN_B - 1) partial[blockIdx.x] = sm[SCAN_B - 1];
}

__global__ void k_scan2(int* partial) {  // single block, NB_SCAN <= 256
    __shared__ int sm[SCAN_B];
    int v = (threadIdx.x < NB_SCAN) ? partial[threadIdx.x] : 0;
    sm[threadIdx.x] = v;
    __syncthreads();
    for (int off = 1; off < SCAN_B; off <<= 1) {
        int add = (threadIdx.x >= off) ? sm[threadIdx.x - off] : 0;
        __syncthreads();
        sm[threadIdx.x] += add;
        __syncthreads();
    }
    if (threadIdx.x < NB_SCAN) partial[threadIdx.x] = sm[threadIdx.x] - v;  // exclusive
}

__global__ void k_scan3(int* __restrict__ rowptr, const int* __restrict__ partial,
                        const int* __restrict__ cntN, float* __restrict__ dinv) {
    int i = blockIdx.x * blockDim.x + threadIdx.x;
    if (i < NN) {
        rowptr[i] += partial[i >> 8];
        dinv[i] = rsqrtf((float)(cntN[i] + 1));  // +1 self-loop
    }
    if (i == NN) rowptr[NN] = NE;
}

// ---------------- in-place exclusive scan of cntBB (bucket-major) ----------------
__global__ __launch_bounds__(256) void k_scanBB(int* __restrict__ cntBB) {
    __shared__ int sm[256];
    const int t = threadIdx.x;
    constexpr int PER = (BBTOT + 255) / 256;  // 151
    const int beg = t * PER;
    const int end = min(beg + PER, BBTOT);
    int s = 0;
    for (int i = beg; i < end; ++i) s += cntBB[i];
    sm[t] = s;
    __syncthreads();
    for (int off = 1; off < 256; off <<= 1) {
        int add = (t >= off) ? sm[t - off] : 0;
        __syncthreads();
        sm[t] += add;
        __syncthreads();
    }
    int run = t ? sm[t - 1] : 0;
    for (int i = beg; i < end; ++i) {
        int v = cntBB[i];
        cntBB[i] = run;
        run += v;
    }
}

// ---------------- pass 2: bin edges into bucket-sorted stage via LDS cursors ----------------
__global__ __launch_bounds__(256) void k_fillP2(const int* __restrict__ src,
                                                const int* __restrict__ dst,
                                                const float* __restrict__ dinv,
                                                const int* __restrict__ cntBB,
                                                uint2* __restrict__ stage) {
    __shared__ int lcur[NBK];
    const int t = threadIdx.x, c = blockIdx.x;
    for (int b = t; b < NBK; b += 256) lcur[b] = cntBB[b * NCH + c];
    __syncthreads();
    const int base = c * CHUNK;
    const int endE = min(base + CHUNK, NE);
    for (int e = base + t; e < endE; e += 256) {
        int s = src[e], d = dst[e];
        float w = dinv[s] * dinv[d];
        __half hw = __float2half(w);
        u32 packed = ((u32)reinterpret_cast<ushort&>(hw) << 16) | (u32)s;
        int slot = atomicAdd(&lcur[d >> 8], 1);
        stage[slot] = make_uint2(packed, (u32)d);
    }
}

// ---------------- pass B: per-bucket block, LDS cursors, bucket-local csr writes ----------------
__global__ __launch_bounds__(256) void k_fillB(const uint2* __restrict__ stage,
                                               const int* __restrict__ cntBB,
                                               const int* __restrict__ rowptr,
                                               u32* __restrict__ csr) {
    __shared__ int cur[256];
    const int b = blockIdx.x;
    const int t = threadIdx.x;
    const int n = b * 256 + t;
    cur[t] = (n < NN) ? rowptr[n] : 0;
    __syncthreads();
    const int beg = cntBB[b * NCH];
    const int end = (b + 1 < NBK) ? cntBB[(b + 1) * NCH] : NE;
    for (int i = beg + t; i < end; i += 256) {
        uint2 en = stage[i];
        int slot = atomicAdd(&cur[en.y & 255u], 1);
        csr[slot] = en.x;
    }
}

// ---------------- gather aggregation over a bf16 table, packed 4B edges ----------------
// out[n] = dinv[n]^2*hb[n] + sum_in w_e * hb[src_e]   (+bias, relu)
template <int D, bool BIAS_RELU, bool BF16OUT>
__global__ __launch_bounds__(256) void k_aggc(const ushort* __restrict__ hb,
                                              const u32* __restrict__ csr,
                                              const int* __restrict__ rowptr,
                                              const float* __restrict__ dinv,
                                              const float* __restrict__ bias,
                                              void* __restrict__ out) {
    constexpr int SUB = D / 8;        // lanes per node (8 for D=64, 16 for D=128)
    constexpr int NPB = 256 / SUB;    // nodes per block
    const int sub = threadIdx.x / SUB;
    const int sl = threadIdx.x % SUB;
    const int node = blockIdx.x * NPB + sub;
    if (node >= NN) return;

    const float dn = dinv[node];
    float acc[8];
    {
        uint4 v = *reinterpret_cast<const uint4*>(hb + (size_t)node * D + sl * 8);
        float w = dn * dn;
        acc[0] = w * blo(v.x); acc[1] = w * bhi(v.x);
        acc[2] = w * blo(v.y); acc[3] = w * bhi(v.y);
        acc[4] = w * blo(v.z); acc[5] = w * bhi(v.z);
        acc[6] = w * blo(v.w); acc[7] = w * bhi(v.w);
    }
    int j = rowptr[node];
    const int end = rowptr[node + 1];
    // peel to 16B boundary for uint4 edge loads
    while ((j & 3) && j < end) {
        u32 e = csr[j];
        uint4 g = *reinterpret_cast<const uint4*>(hb + (size_t)(e & 0xffffu) * D + sl * 8);
        fma8(wof(e), g, acc);
        ++j;
    }
    // main: 4 edges per iteration (one uint4 index load, 4 independent gathers)
    for (; j + 4 <= end; j += 4) {
        uint4 p = *reinterpret_cast<const uint4*>(&csr[j]);
        uint4 g0 = *reinterpret_cast<const uint4*>(hb + (size_t)(p.x & 0xffffu) * D + sl * 8);
        uint4 g1 = *reinterpret_cast<const uint4*>(hb + (size_t)(p.y & 0xffffu) * D + sl * 8);
        uint4 g2 = *reinterpret_cast<const uint4*>(hb + (size_t)(p.z & 0xffffu) * D + sl * 8);
        uint4 g3 = *reinterpret_cast<const uint4*>(hb + (size_t)(p.w & 0xffffu) * D + sl * 8);
        fma8(wof(p.x), g0, acc);
        fma8(wof(p.y), g1, acc);
        fma8(wof(p.z), g2, acc);
        fma8(wof(p.w), g3, acc);
    }
    while (j < end) {
        u32 e = csr[j];
        uint4 g = *reinterpret_cast<const uint4*>(hb + (size_t)(e & 0xffffu) * D + sl * 8);
        fma8(wof(e), g, acc);
        ++j;
    }
    if (BIAS_RELU) {
        float4 b0 = *reinterpret_cast<const float4*>(bias + sl * 8);
        float4 b1 = *reinterpret_cast<const float4*>(bias + sl * 8 + 4);
        acc[0] = fmaxf(acc[0] + b0.x, 0.f); acc[1] = fmaxf(acc[1] + b0.y, 0.f);
        acc[2] = fmaxf(acc[2] + b0.z, 0.f); acc[3] = fmaxf(acc[3] + b0.w, 0.f);
        acc[4] = fmaxf(acc[4] + b1.x, 0.f); acc[5] = fmaxf(acc[5] + b1.y, 0.f);
        acc[6] = fmaxf(acc[6] + b1.z, 0.f); acc[7] = fmaxf(acc[7] + b1.w, 0.f);
    }
    if (BF16OUT) {
        uint4 o;
        o.x = f2b(acc[0]) | (f2b(acc[1]) << 16);
        o.y = f2b(acc[2]) | (f2b(acc[3]) << 16);
        o.z = f2b(acc[4]) | (f2b(acc[5]) << 16);
        o.w = f2b(acc[6]) | (f2b(acc[7]) << 16);
        *reinterpret_cast<uint4*>(reinterpret_cast<ushort*>(out) + (size_t)node * D + sl * 8) = o;
    } else {
        float* op = reinterpret_cast<float*>(out) + (size_t)node * D + sl * 8;
        *reinterpret_cast<float4*>(op) = make_float4(acc[0], acc[1], acc[2], acc[3]);
        *reinterpret_cast<float4*>(op + 4) = make_float4(acc[4], acc[5], acc[6], acc[7]);
    }
}

// ---------------- GEMM: C_bf16[NN,DH] = A_bf16[NN,DIN] @ W_f32[DIN,DH] (+bias, relu) ----------------
__device__ inline float4 fmaf4(float s, float4 w, float4 a) {
    a.x = fmaf(s, w.x, a.x); a.y = fmaf(s, w.y, a.y);
    a.z = fmaf(s, w.z, a.z); a.w = fmaf(s, w.w, a.w);
    return a;
}

template <int DIN, bool BIAS_RELU>
__global__ __launch_bounds__(256) void k_gemm3b(const ushort* __restrict__ A,
                                                const float* __restrict__ W,
                                                const float* __restrict__ bias,
                                                u32* __restrict__ C) {
    constexpr int KT = 32;
    constexpr int NT = DIN / KT;
    constexpr int AP = KT + 4;
    __shared__ float sW[KT * DH];   // [k][c] row-major, 16 KB
    __shared__ float sA[64 * AP];   // [r][k] padded
    const int t = threadIdx.x;
    const int cg = t & 31;
    const int rg = t >> 5;
    const int row0 = blockIdx.x * 64;
    const int sr = t >> 2;
    const int kq = t & 3;

    float4 acc[8];
#pragma unroll
    for (int j = 0; j < 8; ++j) acc[j] = make_float4(0.f, 0.f, 0.f, 0.f);

    for (int tile = 0; tile < NT; ++tile) {
        if (tile) __syncthreads();
        {
            const float4* Wg = reinterpret_cast<const float4*>(W + tile * KT * DH);
            float4* sW4 = reinterpret_cast<float4*>(sW);
#pragma unroll
            for (int i = 0; i < (KT * DH / 4) / 256; ++i)
                sW4[t + 256 * i] = Wg[t + 256 * i];
        }
        {
            int gr = row0 + sr;
            uint4 v = make_uint4(0u, 0u, 0u, 0u);
            if (gr < NN)
                v = *reinterpret_cast<const uint4*>(A + (size_t)gr * DIN + tile * KT + kq * 8);
            *reinterpret_cast<float4*>(&sA[sr * AP + kq * 8]) =
                make_float4(blo(v.x), bhi(v.x), blo(v.y), bhi(v.y));
            *reinterpret_cast<float4*>(&sA[sr * AP + kq * 8 + 4]) =
                make_float4(blo(v.z), bhi(v.z), blo(v.w), bhi(v.w));
        }
        __syncthreads();
#pragma unroll 2
        for (int kk = 0; kk < KT; kk += 4) {
            float4 w0 = *reinterpret_cast<const float4*>(&sW[(kk + 0) * DH + cg * 4]);
            float4 w1 = *reinterpret_cast<const float4*>(&sW[(kk + 1) * DH + cg * 4]);
            float4 w2 = *reinterpret_cast<const float4*>(&sW[(kk + 2) * DH + cg * 4]);
            float4 w3 = *reinterpret_cast<const float4*>(&sW[(kk + 3) * DH + cg * 4]);
#pragma unroll
            for (int j = 0; j < 8; ++j) {
                float4 a = *reinterpret_cast<const float4*>(&sA[(rg * 8 + j) * AP + kk]);
                acc[j] = fmaf4(a.x, w0, acc[j]);
                acc[j] = fmaf4(a.y, w1, acc[j]);
                acc[j] = fmaf4(a.z, w2, acc[j]);
                acc[j] = fmaf4(a.w, w3, acc[j]);
            }
        }
    }
    float4 bb = make_float4(0.f, 0.f, 0.f, 0.f);
    if (BIAS_RELU) bb = *reinterpret_cast<const float4*>(bias + cg * 4);
#pragma unroll
    for (int j = 0; j < 8; ++j) {
        int gr = row0 + rg * 8 + j;
        if (gr < NN) {
            float4 r = acc[j];
            if (BIAS_RELU) {
                r.x = fmaxf(r.x + bb.x, 0.f); r.y = fmaxf(r.y + bb.y, 0.f);
                r.z = fmaxf(r.z + bb.z, 0.f); r.w = fmaxf(r.w + bb.w, 0.f);
            }
            uint2 o = make_uint2(f2b(r.x) | (f2b(r.y) << 16),
                                 f2b(r.z) | (f2b(r.w) << 16));
            *reinterpret_cast<uint2*>(&C[(size_t)gr * (DH / 2) + cg * 2]) = o;
        }
    }
}

// ---------------- pooling (bf16 input, coalesced u32 reads) ----------------
__global__ void k_gstart_zero(const int* __restrict__ batch, int* __restrict__ gstart,
                              float* __restrict__ pooled) {
    int i = blockIdx.x * blockDim.x + threadIdx.x;
    if (i < NG * DH) pooled[i] = 0.0f;
    if (blockIdx.x == 0 && threadIdx.x <= NG) {
        int g = threadIdx.x;
        int lo = 0, hi = NN;
        while (lo < hi) {
            int mid = (lo + hi) >> 1;
            if (batch[mid] < g) lo = mid + 1; else hi = mid;
        }
        gstart[g] = lo;
    }
}

constexpr int POOL_CHUNK = 64;
__global__ __launch_bounds__(256) void k_pool3(const u32* __restrict__ h2b,
                                               const int* __restrict__ batch,
                                               float* __restrict__ pooled) {
    const int c2 = threadIdx.x & 63;   // channel pair (2 bf16 per u32)
    const int q = threadIdx.x >> 6;    // 0..3: 4-way node interleave
    const int n0 = blockIdx.x * POOL_CHUNK;
    const int nEnd = min(n0 + POOL_CHUNK, NN);
    float a0 = 0.f, a1 = 0.f;
    int gcur = -1;
    for (int n = n0 + q; n < nEnd; n += 4) {
        int g = batch[n];
        if (g != gcur) {
            if (gcur >= 0) {
                atomicAdd(&pooled[gcur * DH + c2 * 2], a0);
                atomicAdd(&pooled[gcur * DH + c2 * 2 + 1], a1);
            }
            a0 = a1 = 0.f;
            gcur = g;
        }
        u32 v = h2b[(size_t)n * (DH / 2) + c2];
        a0 += blo(v);
        a1 += bhi(v);
    }
    if (gcur >= 0) {
        atomicAdd(&pooled[gcur * DH + c2 * 2], a0);
        atomicAdd(&pooled[gcur * DH + c2 * 2 + 1], a1);
    }
}

__global__ void k_head(const float* __restrict__ pooled, const int* __restrict__ gstart,
                       const float* __restrict__ Wf, const float* __restrict__ bf,
                       float* __restrict__ out) {
    int t = threadIdx.x;
    if (t >= NG * DO) return;
    int g = t / DO, o = t - g * DO;
    float acc = 0.0f;
    for (int k = 0; k < DH; ++k) acc += pooled[g * DH + k] * Wf[k * DO + o];
    float cnt = fmaxf((float)(gstart[g + 1] - gstart[g]), 1.0f);
    out[t] = acc / cnt + bf[o];
}

extern "C" void kernel_launch(void* const* d_in, const int* in_sizes, int n_in,
                              void* d_out, int out_size, void* d_ws, size_t ws_size,
                              hipStream_t stream) {
    const float* x   = (const float*)d_in[0];
    const int* ei    = (const int*)d_in[1];  // [2, NE] row-major
    const int* batch = (const int*)d_in[2];
    const float* W1  = (const float*)d_in[3];
    const float* b1  = (const float*)d_in[4];
    const float* W2  = (const float*)d_in[5];
    const float* b2  = (const float*)d_in[6];
    const float* Wf  = (const float*)d_in[7];
    const float* bf  = (const float*)d_in[8];
    float* out = (float*)d_out;

    const int* src = ei;
    const int* dst = ei + NE;

    // workspace (4B units; ~42.4 MB total)
    int* cntN     = (int*)d_ws;              // 50048
    int* rowptr   = cntN + 50048;            // 50056 (NN+1 used)
    int* partial  = rowptr + 50056;          // 256
    int* gstart   = partial + 256;           // 80
    int* cntBB    = gstart + 80;             // 38416 ([b][c] bucket-major)
    u32* csr      = (u32*)(cntBB + 38416);   // NE u32 (byte off 555424, 16B-aligned)
    float* dinv   = (float*)(csr + NE);      // 50048
    u32* R1       = (u32*)(dinv + 50048);    // 3.2M units: xb (first 1.6M) then h1b
    u32* R2       = R1 + 3200000;            // 3.2M units: stage/agg1b then tb
    u32* h2b      = R2 + 3200000;            // 3.2M units (NN x 128 bf16)
    float* pooled = (float*)(h2b + 3200000); // 8192

    ushort* xb    = (ushort*)R1;   // NN x 64 bf16 (dead after agg1)
    ushort* h1b   = (ushort*)R1;   // NN x 128 bf16 (written by gemm1, after agg1)
    uint2* stage  = (uint2*)R2;    // NE uint2 = 1.6M u32 (dead after fillB, < agg1 write)
    ushort* agg1b = (ushort*)R2;   // NN x 64 bf16 (dead after gemm1)
    ushort* tb    = (ushort*)R2;   // NN x 128 bf16 (written by gemm2)

    const int B = 256;
    k_init<<<(NN * DI / 8 + B - 1) / B, B, 0, stream>>>(x, (uint4*)xb, cntN);
    k_histc<<<NCH, 256, 0, stream>>>(dst, cntN, cntBB);
    k_scan1<<<NB_SCAN, SCAN_B, 0, stream>>>(cntN, rowptr, partial);
    k_scan2<<<1, SCAN_B, 0, stream>>>(partial);
    k_scan3<<<(NN + B) / B, B, 0, stream>>>(rowptr, partial, cntN, dinv);
    k_scanBB<<<1, 256, 0, stream>>>(cntBB);
    k_fillP2<<<NCH, 256, 0, stream>>>(src, dst, dinv, cntBB, stage);
    k_fillB<<<NBK, 256, 0, stream>>>(stage, cntBB, rowptr, csr);

    const int gemmGrid = (NN + 63) / 64;  // 782

    // layer 1: agg in 64-d (bf16 table), then GEMM (+bias+relu) -> h1 bf16
    k_aggc<DI, false, true><<<(NN + 31) / 32, 256, 0, stream>>>(xb, csr, rowptr, dinv,
                                                                nullptr, agg1b);
    k_gemm3b<DI, true><<<gemmGrid, 256, 0, stream>>>(agg1b, W1, b1, (u32*)h1b);

    // layer 2: GEMM -> t bf16, then agg (+bias+relu) -> h2 bf16
    k_gemm3b<DH, false><<<gemmGrid, 256, 0, stream>>>(h1b, W2, nullptr, (u32*)tb);
    k_aggc<DH, true, true><<<(NN + 15) / 16, 256, 0, stream>>>(tb, csr, rowptr, dinv,
                                                               b2, (void*)h2b);

    // pool + head
    k_gstart_zero<<<32, 256, 0, stream>>>(batch, gstart, pooled);
    k_pool3<<<(NN + POOL_CHUNK - 1) / POOL_CHUNK, 256, 0, stream>>>(h2b, batch, pooled);
    k_head<<<1, 256, 0, stream>>>(pooled, gstart, Wf, bf, out);
}

// Round 14
// 213.359 us; speedup vs baseline: 2.1375x; 1.2657x over previous
//
#include <hip/hip_runtime.h>
#include <hip/hip_fp16.h>

constexpr int NN = 50000;   // nodes
constexpr int NE = 800000;  // edges
constexpr int NG = 64;      // graphs
constexpr int DI = 64;      // in dim
constexpr int DH = 128;     // hidden dim
constexpr int DO = 3;       // out dim

constexpr int SCAN_B = 256;
constexpr int NB_SCAN = (NN + SCAN_B - 1) / SCAN_B;  // 196
constexpr int NBK = 196;                  // dst buckets of 256 nodes (dst >> 8)
constexpr int CHUNK = 4096;               // edges per partition block
constexpr int NCH = (NE + CHUNK - 1) / CHUNK;  // 196 chunks
constexpr int BBTOT = NBK * NCH;          // 38416 (bucket-major [b][c])
constexpr int NBB = (BBTOT + 255) / 256;  // 151 scan blocks

typedef unsigned int u32;

// ---------------- bf16 / fp16 helpers ----------------
__device__ inline float blo(u32 u) { return __uint_as_float(u << 16); }
__device__ inline float bhi(u32 u) { return __uint_as_float(u & 0xffff0000u); }
__device__ inline u32 f2b(float f) {  // RNE round to bf16 (16-bit pattern)
    u32 u = __float_as_uint(f);
    return (u + 0x7fffu + ((u >> 16) & 1u)) >> 16;
}
__device__ inline float wof(u32 e) {  // fp16 weight from high 16 bits
    __half h;
    reinterpret_cast<ushort&>(h) = (ushort)(e >> 16);
    return __half2float(h);
}
__device__ inline void fma8(float w, uint4 v, float acc[8]) {
    acc[0] = fmaf(w, blo(v.x), acc[0]); acc[1] = fmaf(w, bhi(v.x), acc[1]);
    acc[2] = fmaf(w, blo(v.y), acc[2]); acc[3] = fmaf(w, bhi(v.y), acc[3]);
    acc[4] = fmaf(w, blo(v.z), acc[4]); acc[5] = fmaf(w, bhi(v.z), acc[5]);
    acc[6] = fmaf(w, blo(v.w), acc[6]); acc[7] = fmaf(w, bhi(v.w), acc[7]);
}

// ---------------- fused: x -> bf16 AND zero cntN ----------------
__global__ void k_init(const float* __restrict__ x, uint4* __restrict__ xb,
                       int* __restrict__ cntN) {
    int i = blockIdx.x * blockDim.x + threadIdx.x;
    if (i < NN * DI / 8) {
        float4 a = reinterpret_cast<const float4*>(x)[i * 2];
        float4 b = reinterpret_cast<const float4*>(x)[i * 2 + 1];
        uint4 o;
        o.x = f2b(a.x) | (f2b(a.y) << 16);
        o.y = f2b(a.z) | (f2b(a.w) << 16);
        o.z = f2b(b.x) | (f2b(b.y) << 16);
        o.w = f2b(b.z) | (f2b(b.w) << 16);
        xb[i] = o;
    }
    if (i < NN) cntN[i] = 0;
}

// ---------------- hist: per-node in-degree atomics + per-(bucket,chunk) LDS counts ----------------
__global__ __launch_bounds__(256) void k_histc(const int* __restrict__ dst,
                                               int* __restrict__ cntN,
                                               int* __restrict__ cntBB) {
    __shared__ int lcnt[NBK];
    const int t = threadIdx.x, c = blockIdx.x;
    for (int b = t; b < NBK; b += 256) lcnt[b] = 0;
    __syncthreads();
    const int base = c * CHUNK;
    const int endE = min(base + CHUNK, NE);
    for (int e = base + t; e < endE; e += 256) {
        int d = dst[e];
        atomicAdd(&cntN[d], 1);
        atomicAdd(&lcnt[d >> 8], 1);
    }
    __syncthreads();
    for (int b = t; b < NBK; b += 256) cntBB[b * NCH + c] = lcnt[b];
}

// ---------------- rowptr scan (over cntN) ----------------
__global__ void k_scan1(const int* __restrict__ cnt, int* __restrict__ rowptr,
                        int* __restrict__ partial) {
    __shared__ int sm[SCAN_B];
    int i = blockIdx.x * SCAN_B + threadIdx.x;
    int v = (i < NN) ? cnt[i] : 0;
    sm[threadIdx.x] = v;
    __syncthreads();
    for (int off = 1; off < SCAN_B; off <<= 1) {
        int add = (threadIdx.x >= off) ? sm[threadIdx.x - off] : 0;
        __syncthreads();
        sm[threadIdx.x] += add;
        __syncthreads();
    }
    if (i < NN) rowptr[i] = sm[threadIdx.x] - v;  // block-local exclusive
    if (threadIdx.x == SCAN_B - 1) partial[blockIdx.x] = sm[SCAN_B - 1];
}

// generic single-block exclusive scan over n <= 256 entries
__global__ void k_scan2g(int* partial, int n) {
    __shared__ int sm[SCAN_B];
    int v = (threadIdx.x < n) ? partial[threadIdx.x] : 0;
    sm[threadIdx.x] = v;
    __syncthreads();
    for (int off = 1; off < SCAN_B; off <<= 1) {
        int add = (threadIdx.x >= off) ? sm[threadIdx.x - off] : 0;
        __syncthreads();
        sm[threadIdx.x] += add;
        __syncthreads();
    }
    if (threadIdx.x < n) partial[threadIdx.x] = sm[threadIdx.x] - v;  // exclusive
}

__global__ void k_scan3(int* __restrict__ rowptr, const int* __restrict__ partial,
                        const int* __restrict__ cntN, float* __restrict__ dinv) {
    int i = blockIdx.x * blockDim.x + threadIdx.x;
    if (i < NN) {
        rowptr[i] += partial[i >> 8];
        dinv[i] = rsqrtf((float)(cntN[i] + 1));  // +1 self-loop
    }
    if (i == NN) rowptr[NN] = NE;
}

// ---------------- hierarchical scan of cntBB (round-13 lesson: single-block scan = 64us) ----------------
__global__ void k_scanBB1(int* __restrict__ cntBB, int* __restrict__ bbpartial) {
    __shared__ int sm[SCAN_B];
    int i = blockIdx.x * SCAN_B + threadIdx.x;
    int v = (i < BBTOT) ? cntBB[i] : 0;
    sm[threadIdx.x] = v;
    __syncthreads();
    for (int off = 1; off < SCAN_B; off <<= 1) {
        int add = (threadIdx.x >= off) ? sm[threadIdx.x - off] : 0;
        __syncthreads();
        sm[threadIdx.x] += add;
        __syncthreads();
    }
    if (i < BBTOT) cntBB[i] = sm[threadIdx.x] - v;  // in-place block-local exclusive
    if (threadIdx.x == SCAN_B - 1) bbpartial[blockIdx.x] = sm[SCAN_B - 1];
}

__global__ void k_scanBBadd(int* __restrict__ cntBB, const int* __restrict__ bbpartial) {
    int i = blockIdx.x * blockDim.x + threadIdx.x;
    if (i < BBTOT) cntBB[i] += bbpartial[i >> 8];
}

// ---------------- pass 2: bin edges into bucket-sorted stage via LDS cursors ----------------
__global__ __launch_bounds__(256) void k_fillP2(const int* __restrict__ src,
                                                const int* __restrict__ dst,
                                                const float* __restrict__ dinv,
                                                const int* __restrict__ cntBB,
                                                uint2* __restrict__ stage) {
    __shared__ int lcur[NBK];
    const int t = threadIdx.x, c = blockIdx.x;
    for (int b = t; b < NBK; b += 256) lcur[b] = cntBB[b * NCH + c];
    __syncthreads();
    const int base = c * CHUNK;
    const int endE = min(base + CHUNK, NE);
    for (int e = base + t; e < endE; e += 256) {
        int s = src[e], d = dst[e];
        float w = dinv[s] * dinv[d];
        __half hw = __float2half(w);
        u32 packed = ((u32)reinterpret_cast<ushort&>(hw) << 16) | (u32)s;
        int slot = atomicAdd(&lcur[d >> 8], 1);
        stage[slot] = make_uint2(packed, (u32)d);
    }
}

// ---------------- pass B: per-bucket block, LDS cursors, bucket-local csr writes ----------------
__global__ __launch_bounds__(256) void k_fillB(const uint2* __restrict__ stage,
                                               const int* __restrict__ cntBB,
                                               const int* __restrict__ rowptr,
                                               u32* __restrict__ csr) {
    __shared__ int cur[256];
    const int b = blockIdx.x;
    const int t = threadIdx.x;
    const int n = b * 256 + t;
    cur[t] = (n < NN) ? rowptr[n] : 0;
    __syncthreads();
    const int beg = cntBB[b * NCH];
    const int end = (b + 1 < NBK) ? cntBB[(b + 1) * NCH] : NE;
    for (int i = beg + t; i < end; i += 256) {
        uint2 en = stage[i];
        int slot = atomicAdd(&cur[en.y & 255u], 1);
        csr[slot] = en.x;
    }
}

// ---------------- gather aggregation over a bf16 table, packed 4B edges ----------------
// out[n] = dinv[n]^2*hb[n] + sum_in w_e * hb[src_e]   (+bias, relu)
template <int D, bool BIAS_RELU, bool BF16OUT>
__global__ __launch_bounds__(256) void k_aggc(const ushort* __restrict__ hb,
                                              const u32* __restrict__ csr,
                                              const int* __restrict__ rowptr,
                                              const float* __restrict__ dinv,
                                              const float* __restrict__ bias,
                                              void* __restrict__ out) {
    constexpr int SUB = D / 8;        // lanes per node (8 for D=64, 16 for D=128)
    constexpr int NPB = 256 / SUB;    // nodes per block
    const int sub = threadIdx.x / SUB;
    const int sl = threadIdx.x % SUB;
    const int node = blockIdx.x * NPB + sub;
    if (node >= NN) return;

    const float dn = dinv[node];
    float acc[8];
    {
        uint4 v = *reinterpret_cast<const uint4*>(hb + (size_t)node * D + sl * 8);
        float w = dn * dn;
        acc[0] = w * blo(v.x); acc[1] = w * bhi(v.x);
        acc[2] = w * blo(v.y); acc[3] = w * bhi(v.y);
        acc[4] = w * blo(v.z); acc[5] = w * bhi(v.z);
        acc[6] = w * blo(v.w); acc[7] = w * bhi(v.w);
    }
    int j = rowptr[node];
    const int end = rowptr[node + 1];
    // peel to 16B boundary for uint4 edge loads
    while ((j & 3) && j < end) {
        u32 e = csr[j];
        uint4 g = *reinterpret_cast<const uint4*>(hb + (size_t)(e & 0xffffu) * D + sl * 8);
        fma8(wof(e), g, acc);
        ++j;
    }
    // main: 4 edges per iteration (one uint4 index load, 4 independent gathers)
    for (; j + 4 <= end; j += 4) {
        uint4 p = *reinterpret_cast<const uint4*>(&csr[j]);
        uint4 g0 = *reinterpret_cast<const uint4*>(hb + (size_t)(p.x & 0xffffu) * D + sl * 8);
        uint4 g1 = *reinterpret_cast<const uint4*>(hb + (size_t)(p.y & 0xffffu) * D + sl * 8);
        uint4 g2 = *reinterpret_cast<const uint4*>(hb + (size_t)(p.z & 0xffffu) * D + sl * 8);
        uint4 g3 = *reinterpret_cast<const uint4*>(hb + (size_t)(p.w & 0xffffu) * D + sl * 8);
        fma8(wof(p.x), g0, acc);
        fma8(wof(p.y), g1, acc);
        fma8(wof(p.z), g2, acc);
        fma8(wof(p.w), g3, acc);
    }
    while (j < end) {
        u32 e = csr[j];
        uint4 g = *reinterpret_cast<const uint4*>(hb + (size_t)(e & 0xffffu) * D + sl * 8);
        fma8(wof(e), g, acc);
        ++j;
    }
    if (BIAS_RELU) {
        float4 b0 = *reinterpret_cast<const float4*>(bias + sl * 8);
        float4 b1 = *reinterpret_cast<const float4*>(bias + sl * 8 + 4);
        acc[0] = fmaxf(acc[0] + b0.x, 0.f); acc[1] = fmaxf(acc[1] + b0.y, 0.f);
        acc[2] = fmaxf(acc[2] + b0.z, 0.f); acc[3] = fmaxf(acc[3] + b0.w, 0.f);
        acc[4] = fmaxf(acc[4] + b1.x, 0.f); acc[5] = fmaxf(acc[5] + b1.y, 0.f);
        acc[6] = fmaxf(acc[6] + b1.z, 0.f); acc[7] = fmaxf(acc[7] + b1.w, 0.f);
    }
    if (BF16OUT) {
        uint4 o;
        o.x = f2b(acc[0]) | (f2b(acc[1]) << 16);
        o.y = f2b(acc[2]) | (f2b(acc[3]) << 16);
        o.z = f2b(acc[4]) | (f2b(acc[5]) << 16);
        o.w = f2b(acc[6]) | (f2b(acc[7]) << 16);
        *reinterpret_cast<uint4*>(reinterpret_cast<ushort*>(out) + (size_t)node * D + sl * 8) = o;
    } else {
        float* op = reinterpret_cast<float*>(out) + (size_t)node * D + sl * 8;
        *reinterpret_cast<float4*>(op) = make_float4(acc[0], acc[1], acc[2], acc[3]);
        *reinterpret_cast<float4*>(op + 4) = make_float4(acc[4], acc[5], acc[6], acc[7]);
    }
}

// ---------------- GEMM: C_bf16[NN,DH] = A_bf16[NN,DIN] @ W_f32[DIN,DH] (+bias, relu) ----------------
__device__ inline float4 fmaf4(float s, float4 w, float4 a) {
    a.x = fmaf(s, w.x, a.x); a.y = fmaf(s, w.y, a.y);
    a.z = fmaf(s, w.z, a.z); a.w = fmaf(s, w.w, a.w);
    return a;
}

template <int DIN, bool BIAS_RELU>
__global__ __launch_bounds__(256) void k_gemm3b(const ushort* __restrict__ A,
                                                const float* __restrict__ W,
                                                const float* __restrict__ bias,
                                                u32* __restrict__ C) {
    constexpr int KT = 32;
    constexpr int NT = DIN / KT;
    constexpr int AP = KT + 4;
    __shared__ float sW[KT * DH];   // [k][c] row-major, 16 KB
    __shared__ float sA[64 * AP];   // [r][k] padded
    const int t = threadIdx.x;
    const int cg = t & 31;
    const int rg = t >> 5;
    const int row0 = blockIdx.x * 64;
    const int sr = t >> 2;
    const int kq = t & 3;

    float4 acc[8];
#pragma unroll
    for (int j = 0; j < 8; ++j) acc[j] = make_float4(0.f, 0.f, 0.f, 0.f);

    for (int tile = 0; tile < NT; ++tile) {
        if (tile) __syncthreads();
        {
            const float4* Wg = reinterpret_cast<const float4*>(W + tile * KT * DH);
            float4* sW4 = reinterpret_cast<float4*>(sW);
#pragma unroll
            for (int i = 0; i < (KT * DH / 4) / 256; ++i)
                sW4[t + 256 * i] = Wg[t + 256 * i];
        }
        {
            int gr = row0 + sr;
            uint4 v = make_uint4(0u, 0u, 0u, 0u);
            if (gr < NN)
                v = *reinterpret_cast<const uint4*>(A + (size_t)gr * DIN + tile * KT + kq * 8);
            *reinterpret_cast<float4*>(&sA[sr * AP + kq * 8]) =
                make_float4(blo(v.x), bhi(v.x), blo(v.y), bhi(v.y));
            *reinterpret_cast<float4*>(&sA[sr * AP + kq * 8 + 4]) =
                make_float4(blo(v.z), bhi(v.z), blo(v.w), bhi(v.w));
        }
        __syncthreads();
#pragma unroll 2
        for (int kk = 0; kk < KT; kk += 4) {
            float4 w0 = *reinterpret_cast<const float4*>(&sW[(kk + 0) * DH + cg * 4]);
            float4 w1 = *reinterpret_cast<const float4*>(&sW[(kk + 1) * DH + cg * 4]);
            float4 w2 = *reinterpret_cast<const float4*>(&sW[(kk + 2) * DH + cg * 4]);
            float4 w3 = *reinterpret_cast<const float4*>(&sW[(kk + 3) * DH + cg * 4]);
#pragma unroll
            for (int j = 0; j < 8; ++j) {
                float4 a = *reinterpret_cast<const float4*>(&sA[(rg * 8 + j) * AP + kk]);
                acc[j] = fmaf4(a.x, w0, acc[j]);
                acc[j] = fmaf4(a.y, w1, acc[j]);
                acc[j] = fmaf4(a.z, w2, acc[j]);
                acc[j] = fmaf4(a.w, w3, acc[j]);
            }
        }
    }
    float4 bb = make_float4(0.f, 0.f, 0.f, 0.f);
    if (BIAS_RELU) bb = *reinterpret_cast<const float4*>(bias + cg * 4);
#pragma unroll
    for (int j = 0; j < 8; ++j) {
        int gr = row0 + rg * 8 + j;
        if (gr < NN) {
            float4 r = acc[j];
            if (BIAS_RELU) {
                r.x = fmaxf(r.x + bb.x, 0.f); r.y = fmaxf(r.y + bb.y, 0.f);
                r.z = fmaxf(r.z + bb.z, 0.f); r.w = fmaxf(r.w + bb.w, 0.f);
            }
            uint2 o = make_uint2(f2b(r.x) | (f2b(r.y) << 16),
                                 f2b(r.z) | (f2b(r.w) << 16));
            *reinterpret_cast<uint2*>(&C[(size_t)gr * (DH / 2) + cg * 2]) = o;
        }
    }
}

// ---------------- pooling (bf16 input, coalesced u32 reads) ----------------
__global__ void k_gstart_zero(const int* __restrict__ batch, int* __restrict__ gstart,
                              float* __restrict__ pooled) {
    int i = blockIdx.x * blockDim.x + threadIdx.x;
    if (i < NG * DH) pooled[i] = 0.0f;
    if (blockIdx.x == 0 && threadIdx.x <= NG) {
        int g = threadIdx.x;
        int lo = 0, hi = NN;
        while (lo < hi) {
            int mid = (lo + hi) >> 1;
            if (batch[mid] < g) lo = mid + 1; else hi = mid;
        }
        gstart[g] = lo;
    }
}

constexpr int POOL_CHUNK = 64;
__global__ __launch_bounds__(256) void k_pool3(const u32* __restrict__ h2b,
                                               const int* __restrict__ batch,
                                               float* __restrict__ pooled) {
    const int c2 = threadIdx.x & 63;   // channel pair (2 bf16 per u32)
    const int q = threadIdx.x >> 6;    // 0..3: 4-way node interleave
    const int n0 = blockIdx.x * POOL_CHUNK;
    const int nEnd = min(n0 + POOL_CHUNK, NN);
    float a0 = 0.f, a1 = 0.f;
    int gcur = -1;
    for (int n = n0 + q; n < nEnd; n += 4) {
        int g = batch[n];
        if (g != gcur) {
            if (gcur >= 0) {
                atomicAdd(&pooled[gcur * DH + c2 * 2], a0);
                atomicAdd(&pooled[gcur * DH + c2 * 2 + 1], a1);
            }
            a0 = a1 = 0.f;
            gcur = g;
        }
        u32 v = h2b[(size_t)n * (DH / 2) + c2];
        a0 += blo(v);
        a1 += bhi(v);
    }
    if (gcur >= 0) {
        atomicAdd(&pooled[gcur * DH + c2 * 2], a0);
        atomicAdd(&pooled[gcur * DH + c2 * 2 + 1], a1);
    }
}

__global__ void k_head(const float* __restrict__ pooled, const int* __restrict__ gstart,
                       const float* __restrict__ Wf, const float* __restrict__ bf,
                       float* __restrict__ out) {
    int t = threadIdx.x;
    if (t >= NG * DO) return;
    int g = t / DO, o = t - g * DO;
    float acc = 0.0f;
    for (int k = 0; k < DH; ++k) acc += pooled[g * DH + k] * Wf[k * DO + o];
    float cnt = fmaxf((float)(gstart[g + 1] - gstart[g]), 1.0f);
    out[t] = acc / cnt + bf[o];
}

extern "C" void kernel_launch(void* const* d_in, const int* in_sizes, int n_in,
                              void* d_out, int out_size, void* d_ws, size_t ws_size,
                              hipStream_t stream) {
    const float* x   = (const float*)d_in[0];
    const int* ei    = (const int*)d_in[1];  // [2, NE] row-major
    const int* batch = (const int*)d_in[2];
    const float* W1  = (const float*)d_in[3];
    const float* b1  = (const float*)d_in[4];
    const float* W2  = (const float*)d_in[5];
    const float* b2  = (const float*)d_in[6];
    const float* Wf  = (const float*)d_in[7];
    const float* bf  = (const float*)d_in[8];
    float* out = (float*)d_out;

    const int* src = ei;
    const int* dst = ei + NE;

    // workspace (4B units; ~42.4 MB total)
    int* cntN     = (int*)d_ws;              // 50048
    int* rowptr   = cntN + 50048;            // 50056 (NN+1 used)
    int* partial  = rowptr + 50056;          // 256
    int* gstart   = partial + 256;           // 80
    int* cntBB    = gstart + 80;             // 38416 ([b][c] bucket-major)
    int* bbpartial= cntBB + 38416;           // 256
    u32* csr      = (u32*)(bbpartial + 256); // NE u32 (byte off 556448, 16B-aligned)
    float* dinv   = (float*)(csr + NE);      // 50048
    u32* R1       = (u32*)(dinv + 50048);    // 3.2M units: xb (first 1.6M) then h1b
    u32* R2       = R1 + 3200000;            // 3.2M units: stage/agg1b then tb
    u32* h2b      = R2 + 3200000;            // 3.2M units (NN x 128 bf16)
    float* pooled = (float*)(h2b + 3200000); // 8192

    ushort* xb    = (ushort*)R1;   // NN x 64 bf16 (dead after agg1)
    ushort* h1b   = (ushort*)R1;   // NN x 128 bf16 (written by gemm1, after agg1)
    uint2* stage  = (uint2*)R2;    // NE uint2 = 1.6M u32 (dead after fillB, < agg1 write)
    ushort* agg1b = (ushort*)R2;   // NN x 64 bf16 (dead after gemm1)
    ushort* tb    = (ushort*)R2;   // NN x 128 bf16 (written by gemm2)

    const int B = 256;
    k_init<<<(NN * DI / 8 + B - 1) / B, B, 0, stream>>>(x, (uint4*)xb, cntN);
    k_histc<<<NCH, 256, 0, stream>>>(dst, cntN, cntBB);
    k_scan1<<<NB_SCAN, SCAN_B, 0, stream>>>(cntN, rowptr, partial);
    k_scan2g<<<1, SCAN_B, 0, stream>>>(partial, NB_SCAN);
    k_scan3<<<(NN + B) / B, B, 0, stream>>>(rowptr, partial, cntN, dinv);
    k_scanBB1<<<NBB, SCAN_B, 0, stream>>>(cntBB, bbpartial);
    k_scan2g<<<1, SCAN_B, 0, stream>>>(bbpartial, NBB);
    k_scanBBadd<<<NBB, SCAN_B, 0, stream>>>(cntBB, bbpartial);
    k_fillP2<<<NCH, 256, 0, stream>>>(src, dst, dinv, cntBB, stage);
    k_fillB<<<NBK, 256, 0, stream>>>(stage, cntBB, rowptr, csr);

    const int gemmGrid = (NN + 63) / 64;  // 782

    // layer 1: agg in 64-d (bf16 table), then GEMM (+bias+relu) -> h1 bf16
    k_aggc<DI, false, true><<<(NN + 31) / 32, 256, 0, stream>>>(xb, csr, rowptr, dinv,
                                                                nullptr, agg1b);
    k_gemm3b<DI, true><<<gemmGrid, 256, 0, stream>>>(agg1b, W1, b1, (u32*)h1b);

    // layer 2: GEMM -> t bf16, then agg (+bias+relu) -> h2 bf16
    k_gemm3b<DH, false><<<gemmGrid, 256, 0, stream>>>(h1b, W2, nullptr, (u32*)tb);
    k_aggc<DH, true, true><<<(NN + 15) / 16, 256, 0, stream>>>(tb, csr, rowptr, dinv,
                                                               b2, (void*)h2b);

    // pool + head
    k_gstart_zero<<<32, 256, 0, stream>>>(batch, gstart, pooled);
    k_pool3<<<(NN + POOL_CHUNK - 1) / POOL_CHUNK, 256, 0, stream>>>(h2b, batch, pooled);
    k_head<<<1, 256, 0, stream>>>(pooled, gstart, Wf, bf, out);
}

// Round 15
// 198.742 us; speedup vs baseline: 2.2947x; 1.0736x over previous
//
#include <hip/hip_runtime.h>
#include <hip/hip_fp16.h>

constexpr int NN = 50000;   // nodes
constexpr int NE = 800000;  // edges
constexpr int NG = 64;      // graphs
constexpr int DI = 64;      // in dim
constexpr int DH = 128;     // hidden dim
constexpr int DO = 3;       // out dim

constexpr int SCAN_B = 256;
constexpr int NB_SCAN = (NN + SCAN_B - 1) / SCAN_B;  // 196
constexpr int NBK = 196;                  // dst buckets of 256 nodes (dst >> 8)
constexpr int CHUNK = 4096;               // edges per partition block
constexpr int NCH = (NE + CHUNK - 1) / CHUNK;  // 196 chunks
constexpr int BBTOT = NBK * NCH;          // 38416 (bucket-major [b][c])
constexpr int NBB = (BBTOT + 255) / 256;  // 151 scan blocks

typedef unsigned int u32;

// ---------------- bf16 / fp16 helpers ----------------
__device__ inline float blo(u32 u) { return __uint_as_float(u << 16); }
__device__ inline float bhi(u32 u) { return __uint_as_float(u & 0xffff0000u); }
__device__ inline u32 f2b(float f) {  // RNE round to bf16 (16-bit pattern)
    u32 u = __float_as_uint(f);
    return (u + 0x7fffu + ((u >> 16) & 1u)) >> 16;
}
__device__ inline float wof(u32 e) {  // fp16 weight from high 16 bits
    __half h;
    reinterpret_cast<ushort&>(h) = (ushort)(e >> 16);
    return __half2float(h);
}
__device__ inline void fma8(float w, uint4 v, float acc[8]) {
    acc[0] = fmaf(w, blo(v.x), acc[0]); acc[1] = fmaf(w, bhi(v.x), acc[1]);
    acc[2] = fmaf(w, blo(v.y), acc[2]); acc[3] = fmaf(w, bhi(v.y), acc[3]);
    acc[4] = fmaf(w, blo(v.z), acc[4]); acc[5] = fmaf(w, bhi(v.z), acc[5]);
    acc[6] = fmaf(w, blo(v.w), acc[6]); acc[7] = fmaf(w, bhi(v.w), acc[7]);
}

// ---------------- fused: x->bf16, zero cntN, zero pooled, gstart bsearch ----------------
__global__ void k_init(const float* __restrict__ x, uint4* __restrict__ xb,
                       int* __restrict__ cntN, float* __restrict__ pooled,
                       const int* __restrict__ batch, int* __restrict__ gstart) {
    int i = blockIdx.x * blockDim.x + threadIdx.x;
    if (i < NN * DI / 8) {
        float4 a = reinterpret_cast<const float4*>(x)[i * 2];
        float4 b = reinterpret_cast<const float4*>(x)[i * 2 + 1];
        uint4 o;
        o.x = f2b(a.x) | (f2b(a.y) << 16);
        o.y = f2b(a.z) | (f2b(a.w) << 16);
        o.z = f2b(b.x) | (f2b(b.y) << 16);
        o.w = f2b(b.z) | (f2b(b.w) << 16);
        xb[i] = o;
    }
    if (i < NN) cntN[i] = 0;
    if (i < NG * DH) pooled[i] = 0.0f;
    if (blockIdx.x == 0 && threadIdx.x <= NG) {
        int g = threadIdx.x;
        int lo = 0, hi = NN;
        while (lo < hi) {
            int mid = (lo + hi) >> 1;
            if (batch[mid] < g) lo = mid + 1; else hi = mid;
        }
        gstart[g] = lo;
    }
}

// ---------------- hist: per-node in-degree atomics + per-(bucket,chunk) LDS counts ----------------
__global__ __launch_bounds__(256) void k_histc(const int* __restrict__ dst,
                                               int* __restrict__ cntN,
                                               int* __restrict__ cntBB) {
    __shared__ int lcnt[NBK];
    const int t = threadIdx.x, c = blockIdx.x;
    for (int b = t; b < NBK; b += 256) lcnt[b] = 0;
    __syncthreads();
    const int base = c * CHUNK;
    const int endE = min(base + CHUNK, NE);
    for (int e = base + t; e < endE; e += 256) {
        int d = dst[e];
        atomicAdd(&cntN[d], 1);
        atomicAdd(&lcnt[d >> 8], 1);
    }
    __syncthreads();
    for (int b = t; b < NBK; b += 256) cntBB[b * NCH + c] = lcnt[b];
}

// block-local exclusive scan helper (sm shared, returns inclusive in sm)
__device__ inline void blockScan(int* sm) {
    for (int off = 1; off < SCAN_B; off <<= 1) {
        int add = (threadIdx.x >= off) ? sm[threadIdx.x - off] : 0;
        __syncthreads();
        sm[threadIdx.x] += add;
        __syncthreads();
    }
}

// ---------------- merged block-scans: cntN->rowptr (blocks 0..195), cntBB in-place (196..346) ----------------
__global__ void k_scanA(const int* __restrict__ cntN, int* __restrict__ rowptr,
                        int* __restrict__ partial, int* __restrict__ cntBB,
                        int* __restrict__ bbpartial) {
    __shared__ int sm[SCAN_B];
    const int t = threadIdx.x;
    if (blockIdx.x < NB_SCAN) {
        int i = blockIdx.x * SCAN_B + t;
        int v = (i < NN) ? cntN[i] : 0;
        sm[t] = v;
        __syncthreads();
        blockScan(sm);
        if (i < NN) rowptr[i] = sm[t] - v;
        if (t == SCAN_B - 1) partial[blockIdx.x] = sm[SCAN_B - 1];
    } else {
        int bb = blockIdx.x - NB_SCAN;
        int i = bb * SCAN_B + t;
        int v = (i < BBTOT) ? cntBB[i] : 0;
        sm[t] = v;
        __syncthreads();
        blockScan(sm);
        if (i < BBTOT) cntBB[i] = sm[t] - v;
        if (t == SCAN_B - 1) bbpartial[bb] = sm[SCAN_B - 1];
    }
}

// ---------------- 2-block partial scans: block 0 -> partial[196], block 1 -> bbpartial[151] ----------------
__global__ void k_scanB(int* __restrict__ partial, int* __restrict__ bbpartial) {
    __shared__ int sm[SCAN_B];
    int* arr = blockIdx.x ? bbpartial : partial;
    const int n = blockIdx.x ? NBB : NB_SCAN;
    int v = (threadIdx.x < n) ? arr[threadIdx.x] : 0;
    sm[threadIdx.x] = v;
    __syncthreads();
    blockScan(sm);
    if (threadIdx.x < n) arr[threadIdx.x] = sm[threadIdx.x] - v;  // exclusive
}

// ---------------- merged finalize: rowptr+dinv AND cntBB += bbpartial ----------------
__global__ void k_scanC(int* __restrict__ rowptr, const int* __restrict__ partial,
                        const int* __restrict__ cntN, float* __restrict__ dinv,
                        int* __restrict__ cntBB, const int* __restrict__ bbpartial) {
    int i = blockIdx.x * blockDim.x + threadIdx.x;
    if (i < NN) {
        rowptr[i] += partial[i >> 8];
        dinv[i] = rsqrtf((float)(cntN[i] + 1));  // +1 self-loop
    }
    if (i == NN) rowptr[NN] = NE;
    if (i < BBTOT) cntBB[i] += bbpartial[i >> 8];
}

// ---------------- pass 2: bin edges into bucket-sorted stage via LDS cursors ----------------
__global__ __launch_bounds__(256) void k_fillP2(const int* __restrict__ src,
                                                const int* __restrict__ dst,
                                                const float* __restrict__ dinv,
                                                const int* __restrict__ cntBB,
                                                uint2* __restrict__ stage) {
    __shared__ int lcur[NBK];
    const int t = threadIdx.x, c = blockIdx.x;
    for (int b = t; b < NBK; b += 256) lcur[b] = cntBB[b * NCH + c];
    __syncthreads();
    const int base = c * CHUNK;
    const int endE = min(base + CHUNK, NE);
    for (int e = base + t; e < endE; e += 256) {
        int s = src[e], d = dst[e];
        float w = dinv[s] * dinv[d];
        __half hw = __float2half(w);
        u32 packed = ((u32)reinterpret_cast<ushort&>(hw) << 16) | (u32)s;
        int slot = atomicAdd(&lcur[d >> 8], 1);
        stage[slot] = make_uint2(packed, (u32)d);
    }
}

// ---------------- pass B: per-bucket block, LDS cursors, bucket-local csr writes ----------------
__global__ __launch_bounds__(256) void k_fillB(const uint2* __restrict__ stage,
                                               const int* __restrict__ cntBB,
                                               const int* __restrict__ rowptr,
                                               u32* __restrict__ csr) {
    __shared__ int cur[256];
    const int b = blockIdx.x;
    const int t = threadIdx.x;
    const int n = b * 256 + t;
    cur[t] = (n < NN) ? rowptr[n] : 0;
    __syncthreads();
    const int beg = cntBB[b * NCH];
    const int end = (b + 1 < NBK) ? cntBB[(b + 1) * NCH] : NE;
    for (int i = beg + t; i < end; i += 256) {
        uint2 en = stage[i];
        int slot = atomicAdd(&cur[en.y & 255u], 1);
        csr[slot] = en.x;
    }
}

// ---------------- FUSED layer 1: agg (gather over xb) into LDS f32, then GEMM+bias+relu -> h1 bf16 ----------------
__device__ inline float4 fmaf4(float s, float4 w, float4 a) {
    a.x = fmaf(s, w.x, a.x); a.y = fmaf(s, w.y, a.y);
    a.z = fmaf(s, w.z, a.z); a.w = fmaf(s, w.w, a.w);
    return a;
}

__global__ __launch_bounds__(256) void k_aggemm1(const ushort* __restrict__ xb,
                                                 const u32* __restrict__ csr,
                                                 const int* __restrict__ rowptr,
                                                 const float* __restrict__ dinv,
                                                 const float* __restrict__ W,
                                                 const float* __restrict__ bias,
                                                 u32* __restrict__ C) {
    constexpr int AP = DI + 4;  // 68: padded sA row stride
    constexpr int KT = 32;
    __shared__ float sA[64 * AP];   // aggregated A rows, f32 (17.4 KB)
    __shared__ float sW[KT * DH];   // W k-tile (16 KB)
    const int t = threadIdx.x;
    const int row0 = blockIdx.x * 64;

    // ---- phase 1: aggregate this block's 64 rows (2 nodes per 8-lane sub-wave)
    {
        const int sub = t >> 3;  // 0..31
        const int sl = t & 7;    // channels sl*8..sl*8+7
#pragma unroll
        for (int rep = 0; rep < 2; ++rep) {
            const int lr = sub + rep * 32;
            const int node = row0 + lr;
            float acc[8] = {0.f, 0.f, 0.f, 0.f, 0.f, 0.f, 0.f, 0.f};
            if (node < NN) {
                const float dn = dinv[node];
                uint4 v = *reinterpret_cast<const uint4*>(xb + (size_t)node * DI + sl * 8);
                float ws = dn * dn;
                acc[0] = ws * blo(v.x); acc[1] = ws * bhi(v.x);
                acc[2] = ws * blo(v.y); acc[3] = ws * bhi(v.y);
                acc[4] = ws * blo(v.z); acc[5] = ws * bhi(v.z);
                acc[6] = ws * blo(v.w); acc[7] = ws * bhi(v.w);
                int j = rowptr[node];
                const int end = rowptr[node + 1];
                while ((j & 3) && j < end) {
                    u32 e = csr[j];
                    uint4 g = *reinterpret_cast<const uint4*>(xb + (size_t)(e & 0xffffu) * DI + sl * 8);
                    fma8(wof(e), g, acc);
                    ++j;
                }
                for (; j + 4 <= end; j += 4) {
                    uint4 p = *reinterpret_cast<const uint4*>(&csr[j]);
                    uint4 g0 = *reinterpret_cast<const uint4*>(xb + (size_t)(p.x & 0xffffu) * DI + sl * 8);
                    uint4 g1 = *reinterpret_cast<const uint4*>(xb + (size_t)(p.y & 0xffffu) * DI + sl * 8);
                    uint4 g2 = *reinterpret_cast<const uint4*>(xb + (size_t)(p.z & 0xffffu) * DI + sl * 8);
                    uint4 g3 = *reinterpret_cast<const uint4*>(xb + (size_t)(p.w & 0xffffu) * DI + sl * 8);
                    fma8(wof(p.x), g0, acc);
                    fma8(wof(p.y), g1, acc);
                    fma8(wof(p.z), g2, acc);
                    fma8(wof(p.w), g3, acc);
                }
                while (j < end) {
                    u32 e = csr[j];
                    uint4 g = *reinterpret_cast<const uint4*>(xb + (size_t)(e & 0xffffu) * DI + sl * 8);
                    fma8(wof(e), g, acc);
                    ++j;
                }
            }
            *reinterpret_cast<float4*>(&sA[lr * AP + sl * 8]) =
                make_float4(acc[0], acc[1], acc[2], acc[3]);
            *reinterpret_cast<float4*>(&sA[lr * AP + sl * 8 + 4]) =
                make_float4(acc[4], acc[5], acc[6], acc[7]);
        }
    }

    // ---- phase 2: GEMM over K=64 (2 tiles of 32), A from sA (f32, unrounded)
    const int cg = t & 31;
    const int rg = t >> 5;
    float4 acc[8];
#pragma unroll
    for (int j = 0; j < 8; ++j) acc[j] = make_float4(0.f, 0.f, 0.f, 0.f);

#pragma unroll
    for (int tile = 0; tile < 2; ++tile) {
        __syncthreads();  // tile0: sA ready; tile1: prev compute done before sW overwrite
        {
            const float4* Wg = reinterpret_cast<const float4*>(W + tile * KT * DH);
            float4* sW4 = reinterpret_cast<float4*>(sW);
#pragma unroll
            for (int i = 0; i < 4; ++i) sW4[t + 256 * i] = Wg[t + 256 * i];
        }
        __syncthreads();
#pragma unroll 2
        for (int kk = 0; kk < KT; kk += 4) {
            float4 w0 = *reinterpret_cast<const float4*>(&sW[(kk + 0) * DH + cg * 4]);
            float4 w1 = *reinterpret_cast<const float4*>(&sW[(kk + 1) * DH + cg * 4]);
            float4 w2 = *reinterpret_cast<const float4*>(&sW[(kk + 2) * DH + cg * 4]);
            float4 w3 = *reinterpret_cast<const float4*>(&sW[(kk + 3) * DH + cg * 4]);
#pragma unroll
            for (int j = 0; j < 8; ++j) {
                float4 a = *reinterpret_cast<const float4*>(&sA[(rg * 8 + j) * AP + tile * KT + kk]);
                acc[j] = fmaf4(a.x, w0, acc[j]);
                acc[j] = fmaf4(a.y, w1, acc[j]);
                acc[j] = fmaf4(a.z, w2, acc[j]);
                acc[j] = fmaf4(a.w, w3, acc[j]);
            }
        }
    }
    float4 bb = *reinterpret_cast<const float4*>(bias + cg * 4);
#pragma unroll
    for (int j = 0; j < 8; ++j) {
        int gr = row0 + rg * 8 + j;
        if (gr < NN) {
            float4 r = acc[j];
            r.x = fmaxf(r.x + bb.x, 0.f); r.y = fmaxf(r.y + bb.y, 0.f);
            r.z = fmaxf(r.z + bb.z, 0.f); r.w = fmaxf(r.w + bb.w, 0.f);
            uint2 o = make_uint2(f2b(r.x) | (f2b(r.y) << 16),
                                 f2b(r.z) | (f2b(r.w) << 16));
            *reinterpret_cast<uint2*>(&C[(size_t)gr * (DH / 2) + cg * 2]) = o;
        }
    }
}

// ---------------- gather aggregation over a bf16 table (layer 2) ----------------
template <int D, bool BIAS_RELU, bool BF16OUT>
__global__ __launch_bounds__(256) void k_aggc(const ushort* __restrict__ hb,
                                              const u32* __restrict__ csr,
                                              const int* __restrict__ rowptr,
                                              const float* __restrict__ dinv,
                                              const float* __restrict__ bias,
                                              void* __restrict__ out) {
    constexpr int SUB = D / 8;
    constexpr int NPB = 256 / SUB;
    const int sub = threadIdx.x / SUB;
    const int sl = threadIdx.x % SUB;
    const int node = blockIdx.x * NPB + sub;
    if (node >= NN) return;

    const float dn = dinv[node];
    float acc[8];
    {
        uint4 v = *reinterpret_cast<const uint4*>(hb + (size_t)node * D + sl * 8);
        float w = dn * dn;
        acc[0] = w * blo(v.x); acc[1] = w * bhi(v.x);
        acc[2] = w * blo(v.y); acc[3] = w * bhi(v.y);
        acc[4] = w * blo(v.z); acc[5] = w * bhi(v.z);
        acc[6] = w * blo(v.w); acc[7] = w * bhi(v.w);
    }
    int j = rowptr[node];
    const int end = rowptr[node + 1];
    while ((j & 3) && j < end) {
        u32 e = csr[j];
        uint4 g = *reinterpret_cast<const uint4*>(hb + (size_t)(e & 0xffffu) * D + sl * 8);
        fma8(wof(e), g, acc);
        ++j;
    }
    for (; j + 4 <= end; j += 4) {
        uint4 p = *reinterpret_cast<const uint4*>(&csr[j]);
        uint4 g0 = *reinterpret_cast<const uint4*>(hb + (size_t)(p.x & 0xffffu) * D + sl * 8);
        uint4 g1 = *reinterpret_cast<const uint4*>(hb + (size_t)(p.y & 0xffffu) * D + sl * 8);
        uint4 g2 = *reinterpret_cast<const uint4*>(hb + (size_t)(p.z & 0xffffu) * D + sl * 8);
        uint4 g3 = *reinterpret_cast<const uint4*>(hb + (size_t)(p.w & 0xffffu) * D + sl * 8);
        fma8(wof(p.x), g0, acc);
        fma8(wof(p.y), g1, acc);
        fma8(wof(p.z), g2, acc);
        fma8(wof(p.w), g3, acc);
    }
    while (j < end) {
        u32 e = csr[j];
        uint4 g = *reinterpret_cast<const uint4*>(hb + (size_t)(e & 0xffffu) * D + sl * 8);
        fma8(wof(e), g, acc);
        ++j;
    }
    if (BIAS_RELU) {
        float4 b0 = *reinterpret_cast<const float4*>(bias + sl * 8);
        float4 b1 = *reinterpret_cast<const float4*>(bias + sl * 8 + 4);
        acc[0] = fmaxf(acc[0] + b0.x, 0.f); acc[1] = fmaxf(acc[1] + b0.y, 0.f);
        acc[2] = fmaxf(acc[2] + b0.z, 0.f); acc[3] = fmaxf(acc[3] + b0.w, 0.f);
        acc[4] = fmaxf(acc[4] + b1.x, 0.f); acc[5] = fmaxf(acc[5] + b1.y, 0.f);
        acc[6] = fmaxf(acc[6] + b1.z, 0.f); acc[7] = fmaxf(acc[7] + b1.w, 0.f);
    }
    if (BF16OUT) {
        uint4 o;
        o.x = f2b(acc[0]) | (f2b(acc[1]) << 16);
        o.y = f2b(acc[2]) | (f2b(acc[3]) << 16);
        o.z = f2b(acc[4]) | (f2b(acc[5]) << 16);
        o.w = f2b(acc[6]) | (f2b(acc[7]) << 16);
        *reinterpret_cast<uint4*>(reinterpret_cast<ushort*>(out) + (size_t)node * D + sl * 8) = o;
    } else {
        float* op = reinterpret_cast<float*>(out) + (size_t)node * D + sl * 8;
        *reinterpret_cast<float4*>(op) = make_float4(acc[0], acc[1], acc[2], acc[3]);
        *reinterpret_cast<float4*>(op + 4) = make_float4(acc[4], acc[5], acc[6], acc[7]);
    }
}

// ---------------- GEMM (layer 2): C_bf16 = A_bf16 @ W_f32 ----------------
template <int DIN, bool BIAS_RELU>
__global__ __launch_bounds__(256) void k_gemm3b(const ushort* __restrict__ A,
                                                const float* __restrict__ W,
                                                const float* __restrict__ bias,
                                                u32* __restrict__ C) {
    constexpr int KT = 32;
    constexpr int NT = DIN / KT;
    constexpr int AP = KT + 4;
    __shared__ float sW[KT * DH];
    __shared__ float sA[64 * AP];
    const int t = threadIdx.x;
    const int cg = t & 31;
    const int rg = t >> 5;
    const int row0 = blockIdx.x * 64;
    const int sr = t >> 2;
    const int kq = t & 3;

    float4 acc[8];
#pragma unroll
    for (int j = 0; j < 8; ++j) acc[j] = make_float4(0.f, 0.f, 0.f, 0.f);

    for (int tile = 0; tile < NT; ++tile) {
        if (tile) __syncthreads();
        {
            const float4* Wg = reinterpret_cast<const float4*>(W + tile * KT * DH);
            float4* sW4 = reinterpret_cast<float4*>(sW);
#pragma unroll
            for (int i = 0; i < (KT * DH / 4) / 256; ++i)
                sW4[t + 256 * i] = Wg[t + 256 * i];
        }
        {
            int gr = row0 + sr;
            uint4 v = make_uint4(0u, 0u, 0u, 0u);
            if (gr < NN)
                v = *reinterpret_cast<const uint4*>(A + (size_t)gr * DIN + tile * KT + kq * 8);
            *reinterpret_cast<float4*>(&sA[sr * AP + kq * 8]) =
                make_float4(blo(v.x), bhi(v.x), blo(v.y), bhi(v.y));
            *reinterpret_cast<float4*>(&sA[sr * AP + kq * 8 + 4]) =
                make_float4(blo(v.z), bhi(v.z), blo(v.w), bhi(v.w));
        }
        __syncthreads();
#pragma unroll 2
        for (int kk = 0; kk < KT; kk += 4) {
            float4 w0 = *reinterpret_cast<const float4*>(&sW[(kk + 0) * DH + cg * 4]);
            float4 w1 = *reinterpret_cast<const float4*>(&sW[(kk + 1) * DH + cg * 4]);
            float4 w2 = *reinterpret_cast<const float4*>(&sW[(kk + 2) * DH + cg * 4]);
            float4 w3 = *reinterpret_cast<const float4*>(&sW[(kk + 3) * DH + cg * 4]);
#pragma unroll
            for (int j = 0; j < 8; ++j) {
                float4 a = *reinterpret_cast<const float4*>(&sA[(rg * 8 + j) * AP + kk]);
                acc[j] = fmaf4(a.x, w0, acc[j]);
                acc[j] = fmaf4(a.y, w1, acc[j]);
                acc[j] = fmaf4(a.z, w2, acc[j]);
                acc[j] = fmaf4(a.w, w3, acc[j]);
            }
        }
    }
    float4 bb = make_float4(0.f, 0.f, 0.f, 0.f);
    if (BIAS_RELU) bb = *reinterpret_cast<const float4*>(bias + cg * 4);
#pragma unroll
    for (int j = 0; j < 8; ++j) {
        int gr = row0 + rg * 8 + j;
        if (gr < NN) {
            float4 r = acc[j];
            if (BIAS_RELU) {
                r.x = fmaxf(r.x + bb.x, 0.f); r.y = fmaxf(r.y + bb.y, 0.f);
                r.z = fmaxf(r.z + bb.z, 0.f); r.w = fmaxf(r.w + bb.w, 0.f);
            }
            uint2 o = make_uint2(f2b(r.x) | (f2b(r.y) << 16),
                                 f2b(r.z) | (f2b(r.w) << 16));
            *reinterpret_cast<uint2*>(&C[(size_t)gr * (DH / 2) + cg * 2]) = o;
        }
    }
}

// ---------------- pooling (bf16 input, coalesced u32 reads) ----------------
constexpr int POOL_CHUNK = 64;
__global__ __launch_bounds__(256) void k_pool3(const u32* __restrict__ h2b,
                                               const int* __restrict__ batch,
                                               float* __restrict__ pooled) {
    const int c2 = threadIdx.x & 63;
    const int q = threadIdx.x >> 6;
    const int n0 = blockIdx.x * POOL_CHUNK;
    const int nEnd = min(n0 + POOL_CHUNK, NN);
    float a0 = 0.f, a1 = 0.f;
    int gcur = -1;
    for (int n = n0 + q; n < nEnd; n += 4) {
        int g = batch[n];
        if (g != gcur) {
            if (gcur >= 0) {
                atomicAdd(&pooled[gcur * DH + c2 * 2], a0);
                atomicAdd(&pooled[gcur * DH + c2 * 2 + 1], a1);
            }
            a0 = a1 = 0.f;
            gcur = g;
        }
        u32 v = h2b[(size_t)n * (DH / 2) + c2];
        a0 += blo(v);
        a1 += bhi(v);
    }
    if (gcur >= 0) {
        atomicAdd(&pooled[gcur * DH + c2 * 2], a0);
        atomicAdd(&pooled[gcur * DH + c2 * 2 + 1], a1);
    }
}

__global__ void k_head(const float* __restrict__ pooled, const int* __restrict__ gstart,
                       const float* __restrict__ Wf, const float* __restrict__ bf,
                       float* __restrict__ out) {
    int t = threadIdx.x;
    if (t >= NG * DO) return;
    int g = t / DO, o = t - g * DO;
    float acc = 0.0f;
    for (int k = 0; k < DH; ++k) acc += pooled[g * DH + k] * Wf[k * DO + o];
    float cnt = fmaxf((float)(gstart[g + 1] - gstart[g]), 1.0f);
    out[t] = acc / cnt + bf[o];
}

extern "C" void kernel_launch(void* const* d_in, const int* in_sizes, int n_in,
                              void* d_out, int out_size, void* d_ws, size_t ws_size,
                              hipStream_t stream) {
    const float* x   = (const float*)d_in[0];
    const int* ei    = (const int*)d_in[1];  // [2, NE] row-major
    const int* batch = (const int*)d_in[2];
    const float* W1  = (const float*)d_in[3];
    const float* b1  = (const float*)d_in[4];
    const float* W2  = (const float*)d_in[5];
    const float* b2  = (const float*)d_in[6];
    const float* Wf  = (const float*)d_in[7];
    const float* bf  = (const float*)d_in[8];
    float* out = (float*)d_out;

    const int* src = ei;
    const int* dst = ei + NE;

    // workspace (4B units; ~42.4 MB total)
    int* cntN     = (int*)d_ws;              // 50048
    int* rowptr   = cntN + 50048;            // 50056 (NN+1 used)
    int* partial  = rowptr + 50056;          // 256
    int* gstart   = partial + 256;           // 80
    int* cntBB    = gstart + 80;             // 38416 ([b][c] bucket-major)
    int* bbpartial= cntBB + 38416;           // 256
    u32* csr      = (u32*)(bbpartial + 256); // NE u32 (byte off 556448, 16B-aligned)
    float* dinv   = (float*)(csr + NE);      // 50048
    u32* R1       = (u32*)(dinv + 50048);    // 3.2M units: xb (first 1.6M) then h1b
    u32* R2       = R1 + 3200000;            // 3.2M units: stage then tb
    u32* h2b      = R2 + 3200000;            // 3.2M units (NN x 128 bf16)
    float* pooled = (float*)(h2b + 3200000); // 8192

    ushort* xb    = (ushort*)R1;   // NN x 64 bf16 (dead after aggemm1)
    ushort* h1b   = (ushort*)R1 + 1600000 * 2 - 3200000;  // placeholder, set below
    uint2* stage  = (uint2*)R2;    // NE uint2 (dead after fillB)
    ushort* tb    = (ushort*)R2;   // NN x 128 bf16 (written by gemm2 after stage dead)
    h1b = (ushort*)R1;             // NN x 128 bf16? NO — xb still needed by aggemm1.

    // h1b must not alias xb (aggemm1 reads xb while writing h1b).
    // Place h1b in R2's second half?  stage (12.8MB) occupies all of R2 until fillB;
    // aggemm1 runs after fillB, so R2 is free: put h1b at R2, tb at h2b?  tb feeds
    // aggc which writes h2b — conflict.  Simplest safe layout:
    //   h1b -> R2 (stage dead by then), tb -> R1 (xb dead after aggemm1), h2b as-is.
    h1b = (ushort*)R2;
    tb  = (ushort*)R1;

    const int B = 256;
    k_init<<<(NN * DI / 8 + B - 1) / B, B, 0, stream>>>(x, (uint4*)xb, cntN, pooled,
                                                        batch, gstart);
    k_histc<<<NCH, 256, 0, stream>>>(dst, cntN, cntBB);
    k_scanA<<<NB_SCAN + NBB, SCAN_B, 0, stream>>>(cntN, rowptr, partial, cntBB, bbpartial);
    k_scanB<<<2, SCAN_B, 0, stream>>>(partial, bbpartial);
    k_scanC<<<NB_SCAN, SCAN_B, 0, stream>>>(rowptr, partial, cntN, dinv, cntBB, bbpartial);
    k_fillP2<<<NCH, 256, 0, stream>>>(src, dst, dinv, cntBB, stage);
    k_fillB<<<NBK, 256, 0, stream>>>(stage, cntBB, rowptr, csr);

    const int gemmGrid = (NN + 63) / 64;  // 782

    // layer 1 (fused): agg over xb -> LDS f32 -> GEMM+b1+relu -> h1b (in R2; stage dead)
    k_aggemm1<<<gemmGrid, 256, 0, stream>>>(xb, csr, rowptr, dinv, W1, b1, (u32*)h1b);

    // layer 2: GEMM -> tb (in R1; xb dead), then agg (+b2+relu) -> h2b
    k_gemm3b<DH, false><<<gemmGrid, 256, 0, stream>>>(h1b, W2, nullptr, (u32*)tb);
    k_aggc<DH, true, true><<<(NN + 15) / 16, 256, 0, stream>>>(tb, csr, rowptr, dinv,
                                                               b2, (void*)h2b);

    // pool + head
    k_pool3<<<(NN + POOL_CHUNK - 1) / POOL_CHUNK, 256, 0, stream>>>(h2b, batch, pooled);
    k_head<<<1, 256, 0, stream>>>(pooled, gstart, Wf, bf, out);
}

// Round 16
// 174.257 us; speedup vs baseline: 2.6171x; 1.1405x over previous
//
#include <hip/hip_runtime.h>

constexpr int NN = 50000;   // nodes
constexpr int NE = 800000;  // edges
constexpr int NG = 64;      // graphs
constexpr int DI = 64;      // in dim
constexpr int DH = 128;     // hidden dim
constexpr int DO = 3;       // out dim

constexpr int SCAN_B = 256;
constexpr int NBK = 196;                  // dst buckets of 256 nodes (dst >> 8)
constexpr int CHUNK = 4096;               // edges per partition block
constexpr int NCH = (NE + CHUNK - 1) / CHUNK;  // 196 chunks
constexpr int BBTOT = NBK * NCH;          // 38416 (bucket-major [b][c])
constexpr int NBB = (BBTOT + 255) / 256;  // 151 scan blocks

typedef unsigned int u32;

// ---------------- bf16 helpers ----------------
__device__ inline float blo(u32 u) { return __uint_as_float(u << 16); }
__device__ inline float bhi(u32 u) { return __uint_as_float(u & 0xffff0000u); }
__device__ inline u32 f2b(float f) {  // RNE round to bf16 (16-bit pattern)
    u32 u = __float_as_uint(f);
    return (u + 0x7fffu + ((u >> 16) & 1u)) >> 16;
}
__device__ inline void fma8(float w, uint4 v, float acc[8]) {
    acc[0] = fmaf(w, blo(v.x), acc[0]); acc[1] = fmaf(w, bhi(v.x), acc[1]);
    acc[2] = fmaf(w, blo(v.y), acc[2]); acc[3] = fmaf(w, bhi(v.y), acc[3]);
    acc[4] = fmaf(w, blo(v.z), acc[4]); acc[5] = fmaf(w, bhi(v.z), acc[5]);
    acc[6] = fmaf(w, blo(v.w), acc[6]); acc[7] = fmaf(w, bhi(v.w), acc[7]);
}

// ---------------- fused: x->bf16, zero pooled, gstart bsearch ----------------
__global__ void k_init(const float* __restrict__ x, uint4* __restrict__ xb,
                       float* __restrict__ pooled, const int* __restrict__ batch,
                       int* __restrict__ gstart) {
    int i = blockIdx.x * blockDim.x + threadIdx.x;
    if (i < NN * DI / 8) {
        float4 a = reinterpret_cast<const float4*>(x)[i * 2];
        float4 b = reinterpret_cast<const float4*>(x)[i * 2 + 1];
        uint4 o;
        o.x = f2b(a.x) | (f2b(a.y) << 16);
        o.y = f2b(a.z) | (f2b(a.w) << 16);
        o.z = f2b(b.x) | (f2b(b.y) << 16);
        o.w = f2b(b.z) | (f2b(b.w) << 16);
        xb[i] = o;
    }
    if (i < NG * DH) pooled[i] = 0.0f;
    if (blockIdx.x == 0 && threadIdx.x <= NG) {
        int g = threadIdx.x;
        int lo = 0, hi = NN;
        while (lo < hi) {
            int mid = (lo + hi) >> 1;
            if (batch[mid] < g) lo = mid + 1; else hi = mid;
        }
        gstart[g] = lo;
    }
}

// ---------------- hist: per-(bucket,chunk) LDS counts ONLY (no global atomics) ----------------
__global__ __launch_bounds__(256) void k_histc(const int* __restrict__ dst,
                                               int* __restrict__ cntBB) {
    __shared__ int lcnt[NBK];
    const int t = threadIdx.x, c = blockIdx.x;
    for (int b = t; b < NBK; b += 256) lcnt[b] = 0;
    __syncthreads();
    const int base = c * CHUNK;
    const int endE = min(base + CHUNK, NE);
    for (int e = base + t; e < endE; e += 256) atomicAdd(&lcnt[dst[e] >> 8], 1);
    __syncthreads();
    for (int b = t; b < NBK; b += 256) cntBB[b * NCH + c] = lcnt[b];
}

// block-local inclusive scan helper over sm[256]
__device__ inline void blockScan(int* sm) {
    for (int off = 1; off < SCAN_B; off <<= 1) {
        int add = (threadIdx.x >= off) ? sm[threadIdx.x - off] : 0;
        __syncthreads();
        sm[threadIdx.x] += add;
        __syncthreads();
    }
}

// ---------------- cntBB block scans (in place) + per-block sums ----------------
__global__ void k_scanBB1(int* __restrict__ cntBB, int* __restrict__ bbpartial) {
    __shared__ int sm[SCAN_B];
    int i = blockIdx.x * SCAN_B + threadIdx.x;
    int v = (i < BBTOT) ? cntBB[i] : 0;
    sm[threadIdx.x] = v;
    __syncthreads();
    blockScan(sm);
    if (i < BBTOT) cntBB[i] = sm[threadIdx.x] - v;  // block-local exclusive
    if (threadIdx.x == SCAN_B - 1) bbpartial[blockIdx.x] = sm[SCAN_B - 1];
}

__global__ void k_scanB(int* __restrict__ bbpartial) {  // single block, NBB<=256
    __shared__ int sm[SCAN_B];
    int v = (threadIdx.x < NBB) ? bbpartial[threadIdx.x] : 0;
    sm[threadIdx.x] = v;
    __syncthreads();
    blockScan(sm);
    if (threadIdx.x < NBB) bbpartial[threadIdx.x] = sm[threadIdx.x] - v;  // exclusive
}

// ---------------- pass 2: bin (src | dst&255) into bucket-sorted stage via LDS cursors ----------------
__global__ __launch_bounds__(256) void k_fillP2(const int* __restrict__ src,
                                                const int* __restrict__ dst,
                                                const int* __restrict__ cntBB,
                                                const int* __restrict__ bbpartial,
                                                u32* __restrict__ stage) {
    __shared__ int lcur[NBK];
    const int t = threadIdx.x, c = blockIdx.x;
    for (int b = t; b < NBK; b += 256) {
        int i = b * NCH + c;
        lcur[b] = cntBB[i] + bbpartial[i >> 8];
    }
    __syncthreads();
    const int base = c * CHUNK;
    const int endE = min(base + CHUNK, NE);
    for (int e = base + t; e < endE; e += 256) {
        int s = src[e], d = dst[e];
        int slot = atomicAdd(&lcur[d >> 8], 1);
        stage[slot] = ((u32)(d & 255) << 16) | (u32)s;
    }
}

// ---------------- pass B: per-bucket LDS counting sort -> rowptr, dinv, csr16 ----------------
__global__ __launch_bounds__(256) void k_fillB(const u32* __restrict__ stage,
                                               const int* __restrict__ cntBB,
                                               const int* __restrict__ bbpartial,
                                               int* __restrict__ rowptr,
                                               float* __restrict__ dinv,
                                               ushort* __restrict__ csr16) {
    __shared__ int cnt[256];
    __shared__ int sm[256];
    __shared__ int cur[256];
    const int b = blockIdx.x, t = threadIdx.x;
    cnt[t] = 0;
    const int i0 = b * NCH;
    const int beg = cntBB[i0] + bbpartial[i0 >> 8];
    const int end = (b + 1 < NBK) ? cntBB[i0 + NCH] + bbpartial[(i0 + NCH) >> 8] : NE;
    __syncthreads();
    for (int i = beg + t; i < end; i += 256) atomicAdd(&cnt[(stage[i] >> 16) & 255u], 1);
    __syncthreads();
    const int v = cnt[t];
    sm[t] = v;
    __syncthreads();
    blockScan(sm);
    const int excl = sm[t] - v;
    const int n = b * 256 + t;
    if (n < NN) {
        rowptr[n] = beg + excl;
        dinv[n] = rsqrtf((float)(v + 1));  // +1 self-loop
    }
    if (b == NBK - 1 && t == 0) rowptr[NN] = NE;
    cur[t] = beg + excl;
    __syncthreads();
    for (int i = beg + t; i < end; i += 256) {
        u32 e = stage[i];
        int slot = atomicAdd(&cur[(e >> 16) & 255u], 1);
        csr16[slot] = (ushort)(e & 0xffffu);
    }
}

// ---------------- FUSED layer 1+2a: agg(xb) -> LDS f32 -> GEMM W1+b1+relu -> GEMM W2 -> tb bf16 ----------------
__device__ inline float4 fmaf4(float s, float4 w, float4 a) {
    a.x = fmaf(s, w.x, a.x); a.y = fmaf(s, w.y, a.y);
    a.z = fmaf(s, w.z, a.z); a.w = fmaf(s, w.w, a.w);
    return a;
}

__global__ __launch_bounds__(256) void k_aggemm12(const ushort* __restrict__ xb,
                                                  const ushort* __restrict__ csr16,
                                                  const int* __restrict__ rowptr,
                                                  const float* __restrict__ dinv,
                                                  const float* __restrict__ W1,
                                                  const float* __restrict__ b1,
                                                  const float* __restrict__ W2,
                                                  u32* __restrict__ T) {
    constexpr int AP = DI + 4;   // 68: sA stride (phase 1-2)
    constexpr int HP = DH + 4;   // 132: sH stride (phase 3)
    constexpr int KT = 32;
    __shared__ float sAH[64 * HP];   // 8448 f32 (33.8 KB): sA then reused as sH
    __shared__ float sW[KT * DH];    // 4096 f32 (16 KB)
    const int t = threadIdx.x;
    const int row0 = blockIdx.x * 64;

    // ---- phase 1: aggregate 64 rows into sAH (stride AP), w computed from dinv
    {
        const int sub = t >> 3;  // 0..31
        const int sl = t & 7;    // channels sl*8..+7
#pragma unroll
        for (int rep = 0; rep < 2; ++rep) {
            const int lr = sub + rep * 32;
            const int node = row0 + lr;
            float acc[8] = {0.f, 0.f, 0.f, 0.f, 0.f, 0.f, 0.f, 0.f};
            if (node < NN) {
                const float dn = dinv[node];
                uint4 v = *reinterpret_cast<const uint4*>(xb + (size_t)node * DI + sl * 8);
                float ws = dn * dn;
                acc[0] = ws * blo(v.x); acc[1] = ws * bhi(v.x);
                acc[2] = ws * blo(v.y); acc[3] = ws * bhi(v.y);
                acc[4] = ws * blo(v.z); acc[5] = ws * bhi(v.z);
                acc[6] = ws * blo(v.w); acc[7] = ws * bhi(v.w);
                int j = rowptr[node];
                const int end = rowptr[node + 1];
                while ((j & 3) && j < end) {
                    int s = csr16[j];
                    uint4 g = *reinterpret_cast<const uint4*>(xb + (size_t)s * DI + sl * 8);
                    fma8(dn * dinv[s], g, acc);
                    ++j;
                }
                for (; j + 4 <= end; j += 4) {
                    ushort4 q = *reinterpret_cast<const ushort4*>(csr16 + j);
                    uint4 g0 = *reinterpret_cast<const uint4*>(xb + (size_t)q.x * DI + sl * 8);
                    uint4 g1 = *reinterpret_cast<const uint4*>(xb + (size_t)q.y * DI + sl * 8);
                    uint4 g2 = *reinterpret_cast<const uint4*>(xb + (size_t)q.z * DI + sl * 8);
                    uint4 g3 = *reinterpret_cast<const uint4*>(xb + (size_t)q.w * DI + sl * 8);
                    float w0 = dn * dinv[q.x], w1 = dn * dinv[q.y];
                    float w2 = dn * dinv[q.z], w3 = dn * dinv[q.w];
                    fma8(w0, g0, acc);
                    fma8(w1, g1, acc);
                    fma8(w2, g2, acc);
                    fma8(w3, g3, acc);
                }
                while (j < end) {
                    int s = csr16[j];
                    uint4 g = *reinterpret_cast<const uint4*>(xb + (size_t)s * DI + sl * 8);
                    fma8(dn * dinv[s], g, acc);
                    ++j;
                }
            }
            *reinterpret_cast<float4*>(&sAH[lr * AP + sl * 8]) =
                make_float4(acc[0], acc[1], acc[2], acc[3]);
            *reinterpret_cast<float4*>(&sAH[lr * AP + sl * 8 + 4]) =
                make_float4(acc[4], acc[5], acc[6], acc[7]);
        }
    }

    // ---- phase 2: GEMM1 (K=64, 2 tiles), +b1, relu -> h1 in registers
    const int cg = t & 31;
    const int rg = t >> 5;
    float4 acc[8];
#pragma unroll
    for (int j = 0; j < 8; ++j) acc[j] = make_float4(0.f, 0.f, 0.f, 0.f);

#pragma unroll
    for (int tile = 0; tile < 2; ++tile) {
        __syncthreads();  // tile0: sAH ready; tile1: prev reads done before sW overwrite
        {
            const float4* Wg = reinterpret_cast<const float4*>(W1 + tile * KT * DH);
            float4* sW4 = reinterpret_cast<float4*>(sW);
#pragma unroll
            for (int i = 0; i < 4; ++i) sW4[t + 256 * i] = Wg[t + 256 * i];
        }
        __syncthreads();
#pragma unroll 2
        for (int kk = 0; kk < KT; kk += 4) {
            float4 w0 = *reinterpret_cast<const float4*>(&sW[(kk + 0) * DH + cg * 4]);
            float4 w1 = *reinterpret_cast<const float4*>(&sW[(kk + 1) * DH + cg * 4]);
            float4 w2 = *reinterpret_cast<const float4*>(&sW[(kk + 2) * DH + cg * 4]);
            float4 w3 = *reinterpret_cast<const float4*>(&sW[(kk + 3) * DH + cg * 4]);
#pragma unroll
            for (int j = 0; j < 8; ++j) {
                float4 a = *reinterpret_cast<const float4*>(&sAH[(rg * 8 + j) * AP + tile * KT + kk]);
                acc[j] = fmaf4(a.x, w0, acc[j]);
                acc[j] = fmaf4(a.y, w1, acc[j]);
                acc[j] = fmaf4(a.z, w2, acc[j]);
                acc[j] = fmaf4(a.w, w3, acc[j]);
            }
        }
    }
    {
        float4 bb = *reinterpret_cast<const float4*>(b1 + cg * 4);
#pragma unroll
        for (int j = 0; j < 8; ++j) {
            acc[j].x = fmaxf(acc[j].x + bb.x, 0.f);
            acc[j].y = fmaxf(acc[j].y + bb.y, 0.f);
            acc[j].z = fmaxf(acc[j].z + bb.z, 0.f);
            acc[j].w = fmaxf(acc[j].w + bb.w, 0.f);
        }
    }

    // ---- phase 3: h1 -> sAH (stride HP), GEMM2 (K=128, 4 tiles) -> tb bf16
    __syncthreads();  // all phase-2 sAH reads complete before overwrite
#pragma unroll
    for (int j = 0; j < 8; ++j)
        *reinterpret_cast<float4*>(&sAH[(rg * 8 + j) * HP + cg * 4]) = acc[j];

    float4 acc2[8];
#pragma unroll
    for (int j = 0; j < 8; ++j) acc2[j] = make_float4(0.f, 0.f, 0.f, 0.f);

#pragma unroll
    for (int tile = 0; tile < 4; ++tile) {
        __syncthreads();  // tile0: sH writes visible; else: prev reads done
        {
            const float4* Wg = reinterpret_cast<const float4*>(W2 + tile * KT * DH);
            float4* sW4 = reinterpret_cast<float4*>(sW);
#pragma unroll
            for (int i = 0; i < 4; ++i) sW4[t + 256 * i] = Wg[t + 256 * i];
        }
        __syncthreads();
#pragma unroll 2
        for (int kk = 0; kk < KT; kk += 4) {
            float4 w0 = *reinterpret_cast<const float4*>(&sW[(kk + 0) * DH + cg * 4]);
            float4 w1 = *reinterpret_cast<const float4*>(&sW[(kk + 1) * DH + cg * 4]);
            float4 w2 = *reinterpret_cast<const float4*>(&sW[(kk + 2) * DH + cg * 4]);
            float4 w3 = *reinterpret_cast<const float4*>(&sW[(kk + 3) * DH + cg * 4]);
#pragma unroll
            for (int j = 0; j < 8; ++j) {
                float4 a = *reinterpret_cast<const float4*>(&sAH[(rg * 8 + j) * HP + tile * KT + kk]);
                acc2[j] = fmaf4(a.x, w0, acc2[j]);
                acc2[j] = fmaf4(a.y, w1, acc2[j]);
                acc2[j] = fmaf4(a.z, w2, acc2[j]);
                acc2[j] = fmaf4(a.w, w3, acc2[j]);
            }
        }
    }
#pragma unroll
    for (int j = 0; j < 8; ++j) {
        int gr = row0 + rg * 8 + j;
        if (gr < NN) {
            uint2 o = make_uint2(f2b(acc2[j].x) | (f2b(acc2[j].y) << 16),
                                 f2b(acc2[j].z) | (f2b(acc2[j].w) << 16));
            *reinterpret_cast<uint2*>(&T[(size_t)gr * (DH / 2) + cg * 2]) = o;
        }
    }
}

// ---------------- layer-2 aggregation: u16 csr, w from dinv, +b2, relu -> h2 bf16 ----------------
__global__ __launch_bounds__(256) void k_aggd(const ushort* __restrict__ hb,
                                              const ushort* __restrict__ csr16,
                                              const int* __restrict__ rowptr,
                                              const float* __restrict__ dinv,
                                              const float* __restrict__ bias,
                                              u32* __restrict__ out) {
    constexpr int SUB = DH / 8;       // 16 lanes per node
    constexpr int NPB = 256 / SUB;    // 16 nodes per block
    const int sub = threadIdx.x / SUB;
    const int sl = threadIdx.x % SUB;
    const int node = blockIdx.x * NPB + sub;
    if (node >= NN) return;

    const float dn = dinv[node];
    float acc[8];
    {
        uint4 v = *reinterpret_cast<const uint4*>(hb + (size_t)node * DH + sl * 8);
        float w = dn * dn;
        acc[0] = w * blo(v.x); acc[1] = w * bhi(v.x);
        acc[2] = w * blo(v.y); acc[3] = w * bhi(v.y);
        acc[4] = w * blo(v.z); acc[5] = w * bhi(v.z);
        acc[6] = w * blo(v.w); acc[7] = w * bhi(v.w);
    }
    int j = rowptr[node];
    const int end = rowptr[node + 1];
    while ((j & 3) && j < end) {
        int s = csr16[j];
        uint4 g = *reinterpret_cast<const uint4*>(hb + (size_t)s * DH + sl * 8);
        fma8(dn * dinv[s], g, acc);
        ++j;
    }
    for (; j + 4 <= end; j += 4) {
        ushort4 q = *reinterpret_cast<const ushort4*>(csr16 + j);
        uint4 g0 = *reinterpret_cast<const uint4*>(hb + (size_t)q.x * DH + sl * 8);
        uint4 g1 = *reinterpret_cast<const uint4*>(hb + (size_t)q.y * DH + sl * 8);
        uint4 g2 = *reinterpret_cast<const uint4*>(hb + (size_t)q.z * DH + sl * 8);
        uint4 g3 = *reinterpret_cast<const uint4*>(hb + (size_t)q.w * DH + sl * 8);
        float w0 = dn * dinv[q.x], w1 = dn * dinv[q.y];
        float w2 = dn * dinv[q.z], w3 = dn * dinv[q.w];
        fma8(w0, g0, acc);
        fma8(w1, g1, acc);
        fma8(w2, g2, acc);
        fma8(w3, g3, acc);
    }
    while (j < end) {
        int s = csr16[j];
        uint4 g = *reinterpret_cast<const uint4*>(hb + (size_t)s * DH + sl * 8);
        fma8(dn * dinv[s], g, acc);
        ++j;
    }
    {
        float4 b0 = *reinterpret_cast<const float4*>(bias + sl * 8);
        float4 b1v = *reinterpret_cast<const float4*>(bias + sl * 8 + 4);
        acc[0] = fmaxf(acc[0] + b0.x, 0.f); acc[1] = fmaxf(acc[1] + b0.y, 0.f);
        acc[2] = fmaxf(acc[2] + b0.z, 0.f); acc[3] = fmaxf(acc[3] + b0.w, 0.f);
        acc[4] = fmaxf(acc[4] + b1v.x, 0.f); acc[5] = fmaxf(acc[5] + b1v.y, 0.f);
        acc[6] = fmaxf(acc[6] + b1v.z, 0.f); acc[7] = fmaxf(acc[7] + b1v.w, 0.f);
    }
    uint4 o;
    o.x = f2b(acc[0]) | (f2b(acc[1]) << 16);
    o.y = f2b(acc[2]) | (f2b(acc[3]) << 16);
    o.z = f2b(acc[4]) | (f2b(acc[5]) << 16);
    o.w = f2b(acc[6]) | (f2b(acc[7]) << 16);
    *reinterpret_cast<uint4*>(reinterpret_cast<ushort*>(out) + (size_t)node * DH + sl * 8) = o;
}

// ---------------- pooling (bf16 input, coalesced u32 reads) ----------------
constexpr int POOL_CHUNK = 64;
__global__ __launch_bounds__(256) void k_pool3(const u32* __restrict__ h2b,
                                               const int* __restrict__ batch,
                                               float* __restrict__ pooled) {
    const int c2 = threadIdx.x & 63;
    const int q = threadIdx.x >> 6;
    const int n0 = blockIdx.x * POOL_CHUNK;
    const int nEnd = min(n0 + POOL_CHUNK, NN);
    float a0 = 0.f, a1 = 0.f;
    int gcur = -1;
    for (int n = n0 + q; n < nEnd; n += 4) {
        int g = batch[n];
        if (g != gcur) {
            if (gcur >= 0) {
                atomicAdd(&pooled[gcur * DH + c2 * 2], a0);
                atomicAdd(&pooled[gcur * DH + c2 * 2 + 1], a1);
            }
            a0 = a1 = 0.f;
            gcur = g;
        }
        u32 v = h2b[(size_t)n * (DH / 2) + c2];
        a0 += blo(v);
        a1 += bhi(v);
    }
    if (gcur >= 0) {
        atomicAdd(&pooled[gcur * DH + c2 * 2], a0);
        atomicAdd(&pooled[gcur * DH + c2 * 2 + 1], a1);
    }
}

__global__ void k_head(const float* __restrict__ pooled, const int* __restrict__ gstart,
                       const float* __restrict__ Wf, const float* __restrict__ bf,
                       float* __restrict__ out) {
    int t = threadIdx.x;
    if (t >= NG * DO) return;
    int g = t / DO, o = t - g * DO;
    float acc = 0.0f;
    for (int k = 0; k < DH; ++k) acc += pooled[g * DH + k] * Wf[k * DO + o];
    float cnt = fmaxf((float)(gstart[g + 1] - gstart[g]), 1.0f);
    out[t] = acc / cnt + bf[o];
}

extern "C" void kernel_launch(void* const* d_in, const int* in_sizes, int n_in,
                              void* d_out, int out_size, void* d_ws, size_t ws_size,
                              hipStream_t stream) {
    const float* x   = (const float*)d_in[0];
    const int* ei    = (const int*)d_in[1];  // [2, NE] row-major
    const int* batch = (const int*)d_in[2];
    const float* W1  = (const float*)d_in[3];
    const float* b1  = (const float*)d_in[4];
    const float* W2  = (const float*)d_in[5];
    const float* b2  = (const float*)d_in[6];
    const float* Wf  = (const float*)d_in[7];
    const float* bf  = (const float*)d_in[8];
    float* out = (float*)d_out;

    const int* src = ei;
    const int* dst = ei + NE;

    // workspace (4B units; ~37.4 MB total)
    int* rowptr    = (int*)d_ws;               // 50056 (NN+1 used)
    int* bbpartial = rowptr + 50056;           // 256
    int* gstart    = bbpartial + 256;          // 80
    int* cntBB     = gstart + 80;              // 38416 ([b][c] bucket-major)
    ushort* csr16  = (ushort*)(cntBB + 38416); // NE u16 = 400000 u32
    float* dinv    = (float*)((u32*)(cntBB + 38416) + 400000);  // 50048
    u32* xbu       = (u32*)(dinv + 50048);     // 1.6M u32 (NN x 64 bf16)
    u32* stage     = xbu + 1600000;            // 0.8M u32 (NE packed entries)
    u32* tbu       = stage + 800000;           // 3.2M u32 (NN x 128 bf16)
    u32* h2b       = tbu + 3200000;            // 3.2M u32 (NN x 128 bf16)
    float* pooled  = (float*)(h2b + 3200000);  // 8192

    ushort* xb = (ushort*)xbu;
    ushort* tb = (ushort*)tbu;

    const int B = 256;
    k_init<<<(NN * DI / 8 + B - 1) / B, B, 0, stream>>>(x, (uint4*)xb, pooled, batch, gstart);
    k_histc<<<NCH, 256, 0, stream>>>(dst, cntBB);
    k_scanBB1<<<NBB, SCAN_B, 0, stream>>>(cntBB, bbpartial);
    k_scanB<<<1, SCAN_B, 0, stream>>>(bbpartial);
    k_fillP2<<<NCH, 256, 0, stream>>>(src, dst, cntBB, bbpartial, stage);
    k_fillB<<<NBK, 256, 0, stream>>>(stage, cntBB, bbpartial, rowptr, dinv, csr16);

    const int gemmGrid = (NN + 63) / 64;  // 782

    // fused: agg1(xb) -> GEMM W1 + b1 + relu -> GEMM W2 -> tb (bf16)
    k_aggemm12<<<gemmGrid, 256, 0, stream>>>(xb, csr16, rowptr, dinv, W1, b1, W2, tbu);

    // layer-2 agg: gather tb, +b2, relu -> h2b (bf16)
    k_aggd<<<(NN + 15) / 16, 256, 0, stream>>>(tb, csr16, rowptr, dinv, b2, h2b);

    // pool + head
    k_pool3<<<(NN + POOL_CHUNK - 1) / POOL_CHUNK, 256, 0, stream>>>(h2b, batch, pooled);
    k_head<<<1, 256, 0, stream>>>(pooled, gstart, Wf, bf, out);
}

// Round 17
// 168.055 us; speedup vs baseline: 2.7137x; 1.0369x over previous
//
#include <hip/hip_runtime.h>

constexpr int NN = 50000;   // nodes
constexpr int NE = 800000;  // edges
constexpr int NG = 64;      // graphs
constexpr int DI = 64;      // in dim
constexpr int DH = 128;     // hidden dim
constexpr int DO = 3;       // out dim

constexpr int SCAN_B = 256;
constexpr int NBK = 196;                  // dst buckets of 256 nodes (dst >> 8)
constexpr int CHUNK = 4096;               // edges per partition block
constexpr int NCH = (NE + CHUNK - 1) / CHUNK;  // 196 chunks
constexpr int BBTOT = NBK * NCH;          // 38416 (bucket-major [b][c])
constexpr int NBB = (BBTOT + 255) / 256;  // 151 scan blocks

typedef unsigned int u32;

// ---------------- bf16 helpers ----------------
__device__ inline float blo(u32 u) { return __uint_as_float(u << 16); }
__device__ inline float bhi(u32 u) { return __uint_as_float(u & 0xffff0000u); }
__device__ inline u32 f2b(float f) {  // RNE round to bf16 (16-bit pattern)
    u32 u = __float_as_uint(f);
    return (u + 0x7fffu + ((u >> 16) & 1u)) >> 16;
}
__device__ inline void fma8(float w, uint4 v, float acc[8]) {
    acc[0] = fmaf(w, blo(v.x), acc[0]); acc[1] = fmaf(w, bhi(v.x), acc[1]);
    acc[2] = fmaf(w, blo(v.y), acc[2]); acc[3] = fmaf(w, bhi(v.y), acc[3]);
    acc[4] = fmaf(w, blo(v.z), acc[4]); acc[5] = fmaf(w, bhi(v.z), acc[5]);
    acc[6] = fmaf(w, blo(v.w), acc[6]); acc[7] = fmaf(w, bhi(v.w), acc[7]);
}

// ---------------- fused: x->bf16, zero pooled, gstart bsearch ----------------
__global__ void k_init(const float* __restrict__ x, uint4* __restrict__ xb,
                       float* __restrict__ pooled, const int* __restrict__ batch,
                       int* __restrict__ gstart) {
    int i = blockIdx.x * blockDim.x + threadIdx.x;
    if (i < NN * DI / 8) {
        float4 a = reinterpret_cast<const float4*>(x)[i * 2];
        float4 b = reinterpret_cast<const float4*>(x)[i * 2 + 1];
        uint4 o;
        o.x = f2b(a.x) | (f2b(a.y) << 16);
        o.y = f2b(a.z) | (f2b(a.w) << 16);
        o.z = f2b(b.x) | (f2b(b.y) << 16);
        o.w = f2b(b.z) | (f2b(b.w) << 16);
        xb[i] = o;
    }
    if (i < NG * DH) pooled[i] = 0.0f;
    if (blockIdx.x == 0 && threadIdx.x <= NG) {
        int g = threadIdx.x;
        int lo = 0, hi = NN;
        while (lo < hi) {
            int mid = (lo + hi) >> 1;
            if (batch[mid] < g) lo = mid + 1; else hi = mid;
        }
        gstart[g] = lo;
    }
}

// ---------------- hist: per-(bucket,chunk) LDS counts ONLY (no global atomics) ----------------
__global__ __launch_bounds__(256) void k_histc(const int* __restrict__ dst,
                                               int* __restrict__ cntBB) {
    __shared__ int lcnt[NBK];
    const int t = threadIdx.x, c = blockIdx.x;
    for (int b = t; b < NBK; b += 256) lcnt[b] = 0;
    __syncthreads();
    const int base = c * CHUNK;
    const int endE = min(base + CHUNK, NE);
    for (int e = base + t; e < endE; e += 256) atomicAdd(&lcnt[dst[e] >> 8], 1);
    __syncthreads();
    for (int b = t; b < NBK; b += 256) cntBB[b * NCH + c] = lcnt[b];
}

// block-local inclusive scan helper over sm[256]
__device__ inline void blockScan(int* sm) {
    for (int off = 1; off < SCAN_B; off <<= 1) {
        int add = (threadIdx.x >= off) ? sm[threadIdx.x - off] : 0;
        __syncthreads();
        sm[threadIdx.x] += add;
        __syncthreads();
    }
}

// ---------------- cntBB block scans (in place) + per-block sums ----------------
__global__ void k_scanBB1(int* __restrict__ cntBB, int* __restrict__ bbpartial) {
    __shared__ int sm[SCAN_B];
    int i = blockIdx.x * SCAN_B + threadIdx.x;
    int v = (i < BBTOT) ? cntBB[i] : 0;
    sm[threadIdx.x] = v;
    __syncthreads();
    blockScan(sm);
    if (i < BBTOT) cntBB[i] = sm[threadIdx.x] - v;  // block-local exclusive
    if (threadIdx.x == SCAN_B - 1) bbpartial[blockIdx.x] = sm[SCAN_B - 1];
}

__global__ void k_scanB(int* __restrict__ bbpartial) {  // single block, NBB<=256
    __shared__ int sm[SCAN_B];
    int v = (threadIdx.x < NBB) ? bbpartial[threadIdx.x] : 0;
    sm[threadIdx.x] = v;
    __syncthreads();
    blockScan(sm);
    if (threadIdx.x < NBB) bbpartial[threadIdx.x] = sm[threadIdx.x] - v;  // exclusive
}

// ---------------- pass 2: bin (src | dst&255) into bucket-sorted stage via LDS cursors ----------------
__global__ __launch_bounds__(256) void k_fillP2(const int* __restrict__ src,
                                                const int* __restrict__ dst,
                                                const int* __restrict__ cntBB,
                                                const int* __restrict__ bbpartial,
                                                u32* __restrict__ stage) {
    __shared__ int lcur[NBK];
    const int t = threadIdx.x, c = blockIdx.x;
    for (int b = t; b < NBK; b += 256) {
        int i = b * NCH + c;
        lcur[b] = cntBB[i] + bbpartial[i >> 8];
    }
    __syncthreads();
    const int base = c * CHUNK;
    const int endE = min(base + CHUNK, NE);
    for (int e = base + t; e < endE; e += 256) {
        int s = src[e], d = dst[e];
        int slot = atomicAdd(&lcur[d >> 8], 1);
        stage[slot] = ((u32)(d & 255) << 16) | (u32)s;
    }
}

// ---------------- pass B: per-bucket LDS counting sort -> rowptr, dinv, csr16 ----------------
__global__ __launch_bounds__(256) void k_fillB(const u32* __restrict__ stage,
                                               const int* __restrict__ cntBB,
                                               const int* __restrict__ bbpartial,
                                               int* __restrict__ rowptr,
                                               float* __restrict__ dinv,
                                               ushort* __restrict__ csr16) {
    __shared__ int cnt[256];
    __shared__ int sm[256];
    __shared__ int cur[256];
    const int b = blockIdx.x, t = threadIdx.x;
    cnt[t] = 0;
    const int i0 = b * NCH;
    const int beg = cntBB[i0] + bbpartial[i0 >> 8];
    const int end = (b + 1 < NBK) ? cntBB[i0 + NCH] + bbpartial[(i0 + NCH) >> 8] : NE;
    __syncthreads();
    for (int i = beg + t; i < end; i += 256) atomicAdd(&cnt[(stage[i] >> 16) & 255u], 1);
    __syncthreads();
    const int v = cnt[t];
    sm[t] = v;
    __syncthreads();
    blockScan(sm);
    const int excl = sm[t] - v;
    const int n = b * 256 + t;
    if (n < NN) {
        rowptr[n] = beg + excl;
        dinv[n] = rsqrtf((float)(v + 1));  // +1 self-loop
    }
    if (b == NBK - 1 && t == 0) rowptr[NN] = NE;
    cur[t] = beg + excl;
    __syncthreads();
    for (int i = beg + t; i < end; i += 256) {
        u32 e = stage[i];
        int slot = atomicAdd(&cur[(e >> 16) & 255u], 1);
        csr16[slot] = (ushort)(e & 0xffffu);
    }
}

// ---------------- gather aggregation (zero LDS, high occupancy): u16 csr, w from dinv ----------------
template <int D, bool BIAS_RELU>
__global__ __launch_bounds__(256) void k_agge(const ushort* __restrict__ hb,
                                              const ushort* __restrict__ csr16,
                                              const int* __restrict__ rowptr,
                                              const float* __restrict__ dinv,
                                              const float* __restrict__ bias,
                                              u32* __restrict__ out) {
    constexpr int SUB = D / 8;        // lanes per node (8 for D=64, 16 for D=128)
    constexpr int NPB = 256 / SUB;    // nodes per block
    const int sub = threadIdx.x / SUB;
    const int sl = threadIdx.x % SUB;
    const int node = blockIdx.x * NPB + sub;
    if (node >= NN) return;

    const float dn = dinv[node];
    float acc[8];
    {
        uint4 v = *reinterpret_cast<const uint4*>(hb + (size_t)node * D + sl * 8);
        float w = dn * dn;
        acc[0] = w * blo(v.x); acc[1] = w * bhi(v.x);
        acc[2] = w * blo(v.y); acc[3] = w * bhi(v.y);
        acc[4] = w * blo(v.z); acc[5] = w * bhi(v.z);
        acc[6] = w * blo(v.w); acc[7] = w * bhi(v.w);
    }
    int j = rowptr[node];
    const int end = rowptr[node + 1];
    while ((j & 3) && j < end) {
        int s = csr16[j];
        uint4 g = *reinterpret_cast<const uint4*>(hb + (size_t)s * D + sl * 8);
        fma8(dn * dinv[s], g, acc);
        ++j;
    }
    for (; j + 4 <= end; j += 4) {
        ushort4 q = *reinterpret_cast<const ushort4*>(csr16 + j);
        uint4 g0 = *reinterpret_cast<const uint4*>(hb + (size_t)q.x * D + sl * 8);
        uint4 g1 = *reinterpret_cast<const uint4*>(hb + (size_t)q.y * D + sl * 8);
        uint4 g2 = *reinterpret_cast<const uint4*>(hb + (size_t)q.z * D + sl * 8);
        uint4 g3 = *reinterpret_cast<const uint4*>(hb + (size_t)q.w * D + sl * 8);
        float w0 = dn * dinv[q.x], w1 = dn * dinv[q.y];
        float w2 = dn * dinv[q.z], w3 = dn * dinv[q.w];
        fma8(w0, g0, acc);
        fma8(w1, g1, acc);
        fma8(w2, g2, acc);
        fma8(w3, g3, acc);
    }
    while (j < end) {
        int s = csr16[j];
        uint4 g = *reinterpret_cast<const uint4*>(hb + (size_t)s * D + sl * 8);
        fma8(dn * dinv[s], g, acc);
        ++j;
    }
    if (BIAS_RELU) {
        float4 b0 = *reinterpret_cast<const float4*>(bias + sl * 8);
        float4 b1v = *reinterpret_cast<const float4*>(bias + sl * 8 + 4);
        acc[0] = fmaxf(acc[0] + b0.x, 0.f); acc[1] = fmaxf(acc[1] + b0.y, 0.f);
        acc[2] = fmaxf(acc[2] + b0.z, 0.f); acc[3] = fmaxf(acc[3] + b0.w, 0.f);
        acc[4] = fmaxf(acc[4] + b1v.x, 0.f); acc[5] = fmaxf(acc[5] + b1v.y, 0.f);
        acc[6] = fmaxf(acc[6] + b1v.z, 0.f); acc[7] = fmaxf(acc[7] + b1v.w, 0.f);
    }
    uint4 o;
    o.x = f2b(acc[0]) | (f2b(acc[1]) << 16);
    o.y = f2b(acc[2]) | (f2b(acc[3]) << 16);
    o.z = f2b(acc[4]) | (f2b(acc[5]) << 16);
    o.w = f2b(acc[6]) | (f2b(acc[7]) << 16);
    *reinterpret_cast<uint4*>(reinterpret_cast<ushort*>(out) + (size_t)node * D + sl * 8) = o;
}

// ---------------- FUSED double GEMM: agg1b bf16 -> GEMM W1+b1+relu -> (h1 bf16 in LDS) -> GEMM W2 -> tb ----------------
__device__ inline float4 fmaf4(float s, float4 w, float4 a) {
    a.x = fmaf(s, w.x, a.x); a.y = fmaf(s, w.y, a.y);
    a.z = fmaf(s, w.z, a.z); a.w = fmaf(s, w.w, a.w);
    return a;
}

__global__ __launch_bounds__(256) void k_gemm12(const ushort* __restrict__ A,
                                                const float* __restrict__ W1,
                                                const float* __restrict__ b1,
                                                const float* __restrict__ W2,
                                                u32* __restrict__ T) {
    constexpr int AP = DI + 4;   // 68: sA f32 stride
    constexpr int KT = 32;
    __shared__ float sA[64 * AP];   // 17.4 KB; reused as sH (bf16, 64x128 = 16 KB)
    __shared__ float sW[KT * DH];   // 16 KB
    ushort* sH = reinterpret_cast<ushort*>(sA);
    const int t = threadIdx.x;
    const int row0 = blockIdx.x * 64;
    const int cg = t & 31;
    const int rg = t >> 5;

    // ---- stage A (bf16 -> f32 LDS): 64 rows x 64 cols
    {
        const int row = t >> 2;       // 0..63
        const int q2 = (t & 3) * 2;   // uint4-pair index 0,2,4,6
        int gr = row0 + row;
#pragma unroll
        for (int u = 0; u < 2; ++u) {
            uint4 v = make_uint4(0u, 0u, 0u, 0u);
            if (gr < NN)
                v = *reinterpret_cast<const uint4*>(A + (size_t)gr * DI + (q2 + u) * 8);
            *reinterpret_cast<float4*>(&sA[row * AP + (q2 + u) * 8]) =
                make_float4(blo(v.x), bhi(v.x), blo(v.y), bhi(v.y));
            *reinterpret_cast<float4*>(&sA[row * AP + (q2 + u) * 8 + 4]) =
                make_float4(blo(v.z), bhi(v.z), blo(v.w), bhi(v.w));
        }
    }

    // ---- GEMM1: K=64 (2 tiles of 32), +b1, relu -> h1 in registers
    float4 acc[8];
#pragma unroll
    for (int j = 0; j < 8; ++j) acc[j] = make_float4(0.f, 0.f, 0.f, 0.f);

#pragma unroll
    for (int tile = 0; tile < 2; ++tile) {
        __syncthreads();  // tile0: sA ready; tile1: prev sW reads done
        {
            const float4* Wg = reinterpret_cast<const float4*>(W1 + tile * KT * DH);
            float4* sW4 = reinterpret_cast<float4*>(sW);
#pragma unroll
            for (int i = 0; i < 4; ++i) sW4[t + 256 * i] = Wg[t + 256 * i];
        }
        __syncthreads();
#pragma unroll 2
        for (int kk = 0; kk < KT; kk += 4) {
            float4 w0 = *reinterpret_cast<const float4*>(&sW[(kk + 0) * DH + cg * 4]);
            float4 w1 = *reinterpret_cast<const float4*>(&sW[(kk + 1) * DH + cg * 4]);
            float4 w2 = *reinterpret_cast<const float4*>(&sW[(kk + 2) * DH + cg * 4]);
            float4 w3 = *reinterpret_cast<const float4*>(&sW[(kk + 3) * DH + cg * 4]);
#pragma unroll
            for (int j = 0; j < 8; ++j) {
                float4 a = *reinterpret_cast<const float4*>(&sA[(rg * 8 + j) * AP + tile * KT + kk]);
                acc[j] = fmaf4(a.x, w0, acc[j]);
                acc[j] = fmaf4(a.y, w1, acc[j]);
                acc[j] = fmaf4(a.z, w2, acc[j]);
                acc[j] = fmaf4(a.w, w3, acc[j]);
            }
        }
    }
    {
        float4 bb = *reinterpret_cast<const float4*>(b1 + cg * 4);
#pragma unroll
        for (int j = 0; j < 8; ++j) {
            acc[j].x = fmaxf(acc[j].x + bb.x, 0.f);
            acc[j].y = fmaxf(acc[j].y + bb.y, 0.f);
            acc[j].z = fmaxf(acc[j].z + bb.z, 0.f);
            acc[j].w = fmaxf(acc[j].w + bb.w, 0.f);
        }
    }

    // ---- h1 (bf16) -> sH (aliases sA; all sA reads complete first)
    __syncthreads();
#pragma unroll
    for (int j = 0; j < 8; ++j) {
        uint2 o = make_uint2(f2b(acc[j].x) | (f2b(acc[j].y) << 16),
                             f2b(acc[j].z) | (f2b(acc[j].w) << 16));
        *reinterpret_cast<uint2*>(&sH[(rg * 8 + j) * DH + cg * 4]) = o;
    }

    // ---- GEMM2: K=128 (4 tiles of 32) over sH bf16 -> tb bf16
    float4 acc2[8];
#pragma unroll
    for (int j = 0; j < 8; ++j) acc2[j] = make_float4(0.f, 0.f, 0.f, 0.f);

#pragma unroll
    for (int tile = 0; tile < 4; ++tile) {
        __syncthreads();  // tile0: sH writes visible; else: prev sW reads done
        {
            const float4* Wg = reinterpret_cast<const float4*>(W2 + tile * KT * DH);
            float4* sW4 = reinterpret_cast<float4*>(sW);
#pragma unroll
            for (int i = 0; i < 4; ++i) sW4[t + 256 * i] = Wg[t + 256 * i];
        }
        __syncthreads();
#pragma unroll 2
        for (int kk = 0; kk < KT; kk += 4) {
            float4 w0 = *reinterpret_cast<const float4*>(&sW[(kk + 0) * DH + cg * 4]);
            float4 w1 = *reinterpret_cast<const float4*>(&sW[(kk + 1) * DH + cg * 4]);
            float4 w2 = *reinterpret_cast<const float4*>(&sW[(kk + 2) * DH + cg * 4]);
            float4 w3 = *reinterpret_cast<const float4*>(&sW[(kk + 3) * DH + cg * 4]);
#pragma unroll
            for (int j = 0; j < 8; ++j) {
                uint2 av = *reinterpret_cast<const uint2*>(&sH[(rg * 8 + j) * DH + tile * KT + kk]);
                acc2[j] = fmaf4(blo(av.x), w0, acc2[j]);
                acc2[j] = fmaf4(bhi(av.x), w1, acc2[j]);
                acc2[j] = fmaf4(blo(av.y), w2, acc2[j]);
                acc2[j] = fmaf4(bhi(av.y), w3, acc2[j]);
            }
        }
    }
#pragma unroll
    for (int j = 0; j < 8; ++j) {
        int gr = row0 + rg * 8 + j;
        if (gr < NN) {
            uint2 o = make_uint2(f2b(acc2[j].x) | (f2b(acc2[j].y) << 16),
                                 f2b(acc2[j].z) | (f2b(acc2[j].w) << 16));
            *reinterpret_cast<uint2*>(&T[(size_t)gr * (DH / 2) + cg * 2]) = o;
        }
    }
}

// ---------------- pooling (bf16 input, coalesced u32 reads) ----------------
constexpr int POOL_CHUNK = 64;
__global__ __launch_bounds__(256) void k_pool3(const u32* __restrict__ h2b,
                                               const int* __restrict__ batch,
                                               float* __restrict__ pooled) {
    const int c2 = threadIdx.x & 63;
    const int q = threadIdx.x >> 6;
    const int n0 = blockIdx.x * POOL_CHUNK;
    const int nEnd = min(n0 + POOL_CHUNK, NN);
    float a0 = 0.f, a1 = 0.f;
    int gcur = -1;
    for (int n = n0 + q; n < nEnd; n += 4) {
        int g = batch[n];
        if (g != gcur) {
            if (gcur >= 0) {
                atomicAdd(&pooled[gcur * DH + c2 * 2], a0);
                atomicAdd(&pooled[gcur * DH + c2 * 2 + 1], a1);
            }
            a0 = a1 = 0.f;
            gcur = g;
        }
        u32 v = h2b[(size_t)n * (DH / 2) + c2];
        a0 += blo(v);
        a1 += bhi(v);
    }
    if (gcur >= 0) {
        atomicAdd(&pooled[gcur * DH + c2 * 2], a0);
        atomicAdd(&pooled[gcur * DH + c2 * 2 + 1], a1);
    }
}

__global__ void k_head(const float* __restrict__ pooled, const int* __restrict__ gstart,
                       const float* __restrict__ Wf, const float* __restrict__ bf,
                       float* __restrict__ out) {
    int t = threadIdx.x;
    if (t >= NG * DO) return;
    int g = t / DO, o = t - g * DO;
    float acc = 0.0f;
    for (int k = 0; k < DH; ++k) acc += pooled[g * DH + k] * Wf[k * DO + o];
    float cnt = fmaxf((float)(gstart[g + 1] - gstart[g]), 1.0f);
    out[t] = acc / cnt + bf[o];
}

extern "C" void kernel_launch(void* const* d_in, const int* in_sizes, int n_in,
                              void* d_out, int out_size, void* d_ws, size_t ws_size,
                              hipStream_t stream) {
    const float* x   = (const float*)d_in[0];
    const int* ei    = (const int*)d_in[1];  // [2, NE] row-major
    const int* batch = (const int*)d_in[2];
    const float* W1  = (const float*)d_in[3];
    const float* b1  = (const float*)d_in[4];
    const float* W2  = (const float*)d_in[5];
    const float* b2  = (const float*)d_in[6];
    const float* Wf  = (const float*)d_in[7];
    const float* bf  = (const float*)d_in[8];
    float* out = (float*)d_out;

    const int* src = ei;
    const int* dst = ei + NE;

    // workspace (4B units; ~44 MB total)
    int* rowptr    = (int*)d_ws;               // 50056 (NN+1 used)
    int* bbpartial = rowptr + 50056;           // 256
    int* gstart    = bbpartial + 256;          // 80
    int* cntBB     = gstart + 80;              // 38416 ([b][c] bucket-major)
    ushort* csr16  = (ushort*)(cntBB + 38416); // NE u16 = 400000 u32
    float* dinv    = (float*)((u32*)(cntBB + 38416) + 400000);  // 50048
    u32* xbu       = (u32*)(dinv + 50048);     // 1.6M u32 (NN x 64 bf16)
    u32* stage     = xbu + 1600000;            // 0.8M u32 (NE packed entries)
    u32* agg1bu    = stage + 800000;           // 1.6M u32 (NN x 64 bf16)
    u32* tbu       = agg1bu + 1600000;         // 3.2M u32 (NN x 128 bf16)
    u32* h2b       = tbu + 3200000;            // 3.2M u32 (NN x 128 bf16)
    float* pooled  = (float*)(h2b + 3200000);  // 8192

    ushort* xb    = (ushort*)xbu;
    ushort* agg1b = (ushort*)agg1bu;
    ushort* tb    = (ushort*)tbu;

    const int B = 256;
    k_init<<<(NN * DI / 8 + B - 1) / B, B, 0, stream>>>(x, (uint4*)xb, pooled, batch, gstart);
    k_histc<<<NCH, 256, 0, stream>>>(dst, cntBB);
    k_scanBB1<<<NBB, SCAN_B, 0, stream>>>(cntBB, bbpartial);
    k_scanB<<<1, SCAN_B, 0, stream>>>(bbpartial);
    k_fillP2<<<NCH, 256, 0, stream>>>(src, dst, cntBB, bbpartial, stage);
    k_fillB<<<NBK, 256, 0, stream>>>(stage, cntBB, bbpartial, rowptr, dinv, csr16);

    const int gemmGrid = (NN + 63) / 64;  // 782

    // layer 1 agg (zero-LDS, high occupancy): gather xb -> agg1b bf16
    k_agge<DI, false><<<(NN + 31) / 32, 256, 0, stream>>>(xb, csr16, rowptr, dinv,
                                                          nullptr, agg1bu);
    // fused GEMM1+GEMM2: agg1b -> h1 (LDS bf16) -> tb
    k_gemm12<<<gemmGrid, 256, 0, stream>>>(agg1b, W1, b1, W2, tbu);

    // layer-2 agg: gather tb, +b2, relu -> h2b (bf16)
    k_agge<DH, true><<<(NN + 15) / 16, 256, 0, stream>>>(tb, csr16, rowptr, dinv, b2, h2b);

    // pool + head
    k_pool3<<<(NN + POOL_CHUNK - 1) / POOL_CHUNK, 256, 0, stream>>>(h2b, batch, pooled);
    k_head<<<1, 256, 0, stream>>>(pooled, gstart, Wf, bf, out);
}